// Round 13
// baseline (362.246 us; speedup 1.0000x reference)
//
#include <hip/hip_runtime.h>
#include <stdint.h>

// ---- dims ----
// B=8, L=27, T=256, D=1152, GS=3, G=9, DD=512, H=8, HD=64, NQ=1, OD=2048
// Output dtype: FLOAT32 (verified round 4).
//
// Round 13: streaming-efficiency round (r12 streamers ran ~1.5-2 TB/s vs
// 6.8 TB/s measured fill-rate):
//   score_k: LDS-staged [64t][192d] tiles, coalesced float4 K loads,
//            stride-195 LDS (conflict-free column reads), writes final
//            scores[bl][t][h] (no psc quarters).
//   va_k   : float2 lanes, t-quarter split -> 864 blocks / 30 waves/CU,
//            deterministic 4-partial VAp (summed in pv_mat).
// Algebra (verified r9-r12): scores = K·Qk (bk cancels in softmax);
// pooled = (attn·V)·Wv + bv. All f32.

// ---------------------------------------------------------------------------
// K1: Qp[l,f] = (query[l,:] @ Wq[g] + bq[g]) * 0.125
// grid (27,8), block 256.
// ---------------------------------------------------------------------------
__global__ __launch_bounds__(256) void qproj(
    const float* __restrict__ query, const float* __restrict__ Wq,
    const float* __restrict__ bq, float* __restrict__ Qp)
{
  const int l = blockIdx.x, g = l / 3;
  const int fb = blockIdx.y * 64;
  __shared__ float q[1152];
  __shared__ float part[4][64];
  for (int i = threadIdx.x; i < 1152; i += 256) q[i] = query[(size_t)l * 1152 + i];
  __syncthreads();
  const int fi = threadIdx.x & 63;
  const int kq = threadIdx.x >> 6;            // 0..3, 288 d's each
  const float* W = Wq + (size_t)g * 1152 * 512 + fb + fi;
  float a0 = 0.f, a1 = 0.f;
  const int d0 = kq * 288;
#pragma unroll 4
  for (int d = d0; d < d0 + 288; d += 2) {
    a0 += q[d]     * W[(size_t)d * 512];
    a1 += q[d + 1] * W[(size_t)(d + 1) * 512];
  }
  part[kq][fi] = a0 + a1;
  __syncthreads();
  if (threadIdx.x < 64) {
    const int f = fb + threadIdx.x;
    float r = part[0][threadIdx.x] + part[1][threadIdx.x]
            + part[2][threadIdx.x] + part[3][threadIdx.x];
    Qp[l * 512 + f] = (r + bq[g * 512 + f]) * 0.125f;
  }
}

// ---------------------------------------------------------------------------
// K2: Qk[l,d,h] = sum_e Qp[l,h*64+e] * Wk[g,d,h*64+e]    (layout [l][d][h])
// grid 3888, block 256: 4 threads per (l,h,d), 2-level shuffle reduce.
// ---------------------------------------------------------------------------
__global__ __launch_bounds__(256) void qk_mat(
    const float* __restrict__ Qp, const float* __restrict__ Wk,
    float* __restrict__ Qk)
{
  const int gidx = blockIdx.x * 256 + threadIdx.x;  // 0..995327
  const int eg   = gidx & 3;
  const int item = gidx >> 2;         // 0..248831 = (l,h,d)
  const int l    = item / 9216;
  const int rem  = item % 9216;
  const int h    = rem / 1152;
  const int d    = rem % 1152;
  const int g    = l / 3;
  const float4* q4 = (const float4*)(Qp + l * 512 + h * 64 + eg * 16);
  const float4* w4 = (const float4*)(Wk + (size_t)g * 1152 * 512 + (size_t)d * 512 + h * 64 + eg * 16);
  float acc = 0.f;
#pragma unroll
  for (int e = 0; e < 4; e++) {
    const float4 a = q4[e], b = w4[e];
    acc += a.x * b.x + a.y * b.y + a.z * b.z + a.w * b.w;
  }
  acc += __shfl_xor(acc, 1, 64);
  acc += __shfl_xor(acc, 2, 64);
  if (eg == 0) Qk[((size_t)l * 1152 + d) * 8 + h] = acc;
}

// ---------------------------------------------------------------------------
// K3a: scores[bl][t][h] = sum_d K[bl,t,d] * Qk[l,d,h]
// grid (216,4 token-tiles), block 256 = (tt 64 tokens x ds 4 d-quarters).
// 6 chunks of 192 d: coalesced float4 K loads -> LDS[64][195] (stride 195:
// odd, 195%32=3 -> column reads 2 lanes/bank = free) -> scalar compute with
// wave-uniform Qk s_loads. In-block ds-reduce writes final scores.
// ---------------------------------------------------------------------------
__global__ __launch_bounds__(256) void score_k(
    const float* __restrict__ K, const float* __restrict__ Qk,
    float* __restrict__ scores)
{
  const int bl = blockIdx.x;          // 0..215
  const int tq = blockIdx.y;          // 0..3 (64-token tile)
  const int l = bl % 27;
  const int tid = threadIdx.x;
  const int tt = tid & 63;            // token within tile
  const int ds = tid >> 6;            // d-subchunk (48 floats of each 192)

  __shared__ float lds[64 * 195];     // 49,920 B; also reused for reduce

  const float* Kbase = K + ((size_t)bl * 256 + tq * 64) * 1152;
  const float* qkl = Qk + (size_t)l * 1152 * 8;

  float sc[8] = {0.f, 0.f, 0.f, 0.f, 0.f, 0.f, 0.f, 0.f};

  for (int dc = 0; dc < 6; dc++) {
    __syncthreads();                  // protect lds from previous reads
    // stage: 64 rows x 192 floats = 3072 float4; 12 iters x 256 threads
#pragma unroll
    for (int it = 0; it < 12; it++) {
      const int flat = it * 256 + tid;       // float4 slot
      const int row = flat / 48, col = flat % 48;
      const float4 v = *(const float4*)(Kbase + (size_t)row * 1152 + dc * 192 + col * 4);
      float* p = &lds[row * 195 + col * 4];
      p[0] = v.x; p[1] = v.y; p[2] = v.z; p[3] = v.w;
    }
    __syncthreads();
    const float* q0 = qkl + (size_t)(dc * 192 + ds * 48) * 8;  // wave-uniform
    const float* krow = &lds[tt * 195 + ds * 48];
#pragma unroll 6
    for (int j = 0; j < 48; j++) {
      const float kv = krow[j];
      const float* q = q0 + j * 8;
#pragma unroll
      for (int h = 0; h < 8; h++) sc[h] = fmaf(kv, q[h], sc[h]);
    }
  }

  // reduce the 4 ds-partials per (tt, h) via LDS
  __syncthreads();
#pragma unroll
  for (int h = 0; h < 8; h++) lds[(ds * 64 + tt) * 8 + h] = sc[h];
  __syncthreads();
  if (tid < 64) {
    float* dst = scores + ((size_t)bl * 256 + tq * 64 + tid) * 8;
#pragma unroll
    for (int h = 0; h < 8; h++)
      dst[h] = (lds[(0 * 64 + tid) * 8 + h] + lds[(1 * 64 + tid) * 8 + h])
             + (lds[(2 * 64 + tid) * 8 + h] + lds[(3 * 64 + tid) * 8 + h]);
  }
}

// ---------------------------------------------------------------------------
// K3b: softmax over 256 tokens per (bl,h). grid 216, block 256 (thread = t).
// attn[bl][t][h].
// ---------------------------------------------------------------------------
__global__ __launch_bounds__(256) void softmax_k(
    const float* __restrict__ scores, float* __restrict__ attn)
{
  const int bl = blockIdx.x;
  const int t = threadIdx.x;
  const int wid = t >> 6, lane = t & 63;
  __shared__ float red[4][8], red2[4][8];

  float sc[8];
  const float* src = scores + ((size_t)bl * 256 + t) * 8;
#pragma unroll
  for (int h = 0; h < 8; h++) sc[h] = src[h];
#pragma unroll
  for (int h = 0; h < 8; h++) {
    float m = sc[h];
#pragma unroll
    for (int o = 1; o < 64; o <<= 1) m = fmaxf(m, __shfl_xor(m, o, 64));
    if (lane == 0) red[wid][h] = m;
  }
  __syncthreads();
  float p[8];
#pragma unroll
  for (int h = 0; h < 8; h++) {
    const float M = fmaxf(fmaxf(red[0][h], red[1][h]), fmaxf(red[2][h], red[3][h]));
    p[h] = __expf(sc[h] - M);
    float s = p[h];
#pragma unroll
    for (int o = 1; o < 64; o <<= 1) s += __shfl_xor(s, o, 64);
    if (lane == 0) red2[wid][h] = s;
  }
  __syncthreads();
  float* dst = attn + ((size_t)bl * 256 + t) * 8;
#pragma unroll
  for (int h = 0; h < 8; h++) {
    const float S = red2[0][h] + red2[1][h] + red2[2][h] + red2[3][h];
    dst[h] = p[h] * (1.0f / S);
  }
}

// ---------------------------------------------------------------------------
// K3c: VAp[tq][bl][h][d] = sum_{t in quarter} attn[bl][t][h] * V[bl,t,d]
// grid (216,4), block 576 (9 waves; d = w*128 + lane*2, float2 coalesced).
// attn via wave-uniform s_loads. No LDS. Deterministic partials.
// ---------------------------------------------------------------------------
__global__ __launch_bounds__(576) void va_k(
    const float* __restrict__ V, const float* __restrict__ attn,
    float* __restrict__ VAp)
{
  const int bl = blockIdx.x;          // 0..215
  const int tq = blockIdx.y;          // 0..3 (64-token quarter)
  const int w = threadIdx.x >> 6, lane = threadIdx.x & 63;
  const int d = w * 128 + lane * 2;   // 0..1150

  const float* Vbase = V + ((size_t)bl * 256 + tq * 64) * 1152 + d;
  const float* ab = attn + ((size_t)bl * 256 + tq * 64) * 8;   // uniform

  float2 acc[8];
#pragma unroll
  for (int h = 0; h < 8; h++) acc[h] = make_float2(0.f, 0.f);

#pragma unroll 4
  for (int t = 0; t < 64; t++) {
    const float2 v = *(const float2*)(Vbase + (size_t)t * 1152);
    const float* av = ab + t * 8;     // uniform -> s_load_dwordx8
#pragma unroll
    for (int h = 0; h < 8; h++) {
      acc[h].x = fmaf(av[h], v.x, acc[h].x);
      acc[h].y = fmaf(av[h], v.y, acc[h].y);
    }
  }
  float* dst = VAp + (((size_t)tq * 216 + bl) * 8) * 1152 + d;
#pragma unroll
  for (int h = 0; h < 8; h++)
    *(float2*)(dst + (size_t)h * 1152) = acc[h];
}

// ---------------------------------------------------------------------------
// K4: psum[dz][bl][e*8+h] = sum_{d in quarter dz} (sum_tq VAp) * Wv
// grid (27,8,4) = (l,h,dz); block 512 = 8 waves (wave = b), lane = e.
// ---------------------------------------------------------------------------
__global__ __launch_bounds__(512) void pv_mat(
    const float* __restrict__ VAp, const float* __restrict__ Wv,
    float* __restrict__ psum)
{
  const int l = blockIdx.x, g = l / 3, h = blockIdx.y, dz = blockIdx.z;
  const int b = threadIdx.x >> 6, lane = threadIdx.x & 63;
  const int bl = b * 27 + l;
  const float* W = Wv + (size_t)g * 1152 * 512 + h * 64 + lane;
  const size_t stride = (size_t)216 * 8 * 1152;
  const float* v0 = VAp + ((size_t)bl * 8 + h) * 1152;
  const float* v1 = v0 + stride;
  const float* v2 = v1 + stride;
  const float* v3 = v2 + stride;
  const int d0 = dz * 288;
  float a0 = 0.f, a1 = 0.f;
#pragma unroll 4
  for (int d = d0; d < d0 + 288; d += 2) {
    const float va  = (v0[d]     + v1[d])     + (v2[d]     + v3[d]);
    const float vb  = (v0[d + 1] + v1[d + 1]) + (v2[d + 1] + v3[d + 1]);
    a0 = fmaf(va, W[(size_t)d * 512],       a0);
    a1 = fmaf(vb, W[(size_t)(d + 1) * 512], a1);
  }
  psum[((size_t)dz * 216 + bl) * 512 + lane * 8 + h] = a0 + a1;
}

// ---------------------------------------------------------------------------
// K5: out[bl,n] = pooled[bl,:]@Wo[g] + bo[g];  pooled = sum_dz psum + bv_perm
// grid (27,8), block 256.
// ---------------------------------------------------------------------------
__global__ __launch_bounds__(256) void out_gemm(
    const float* __restrict__ psum, const float* __restrict__ bv,
    const float* __restrict__ Wo, const float* __restrict__ bo,
    float* __restrict__ out)
{
  const int l = blockIdx.x, g = l / 3;
  const int n = blockIdx.y * 256 + threadIdx.x;
  __shared__ float pl[8][512];
  for (int i = threadIdx.x; i < 4096; i += 256) {
    const int b = i >> 9, f = i & 511;
    const int bl = b * 27 + l;
    const int e = f >> 3, h = f & 7;           // f = e*8 + h
    float v = bv[g * 512 + h * 64 + e];
#pragma unroll
    for (int dz = 0; dz < 4; dz++)
      v += psum[((size_t)dz * 216 + bl) * 512 + f];
    pl[b][f] = v;
  }
  __syncthreads();
  const float* W = Wo + (size_t)g * 512 * 2048 + n;
  float acc[8] = {0.f, 0.f, 0.f, 0.f, 0.f, 0.f, 0.f, 0.f};
#pragma unroll 4
  for (int f = 0; f < 512; f++) {
    const float w = W[(size_t)f * 2048];
#pragma unroll
    for (int b = 0; b < 8; b++) acc[b] += pl[b][f] * w;
  }
  const float bb = bo[g * 2048 + n];
#pragma unroll
  for (int b = 0; b < 8; b++)
    out[(size_t)(b * 27 + l) * 2048 + n] = acc[b] + bb;
}

// ---------------------------------------------------------------------------
// sentinel: zero-fill f32 output (absmax would read ~1.06e-1 = max|ref|)
// ---------------------------------------------------------------------------
__global__ __launch_bounds__(256) void zfill(float* __restrict__ out, int n) {
  const int i = blockIdx.x * 256 + threadIdx.x;
  if (i < n) out[i] = 0.f;
}

// ---------------------------------------------------------------------------
extern "C" void kernel_launch(void* const* d_in, const int* in_sizes, int n_in,
                              void* d_out, int out_size, void* d_ws, size_t ws_size,
                              hipStream_t stream)
{
  float* out = (float*)d_out;   // f32 output (verified round 4)

  // ---- config guards ----
  bool ok = (n_in == 11) && (out_size == 8 * 27 * 2048);
  if (ok) {
    const int expect[11] = {
      8 * 27 * 256 * 1152,  // K
      8 * 27 * 256 * 1152,  // V
      27 * 1 * 1152,        // query
      9 * 1152 * 512,       // Wq
      9 * 512,              // bq
      9 * 1152 * 512,       // Wk
      9 * 512,              // bk
      9 * 1152 * 512,       // Wv
      9 * 512,              // bv
      9 * 512 * 2048,       // Wo
      9 * 2048              // bo
    };
    for (int i = 0; i < 11; i++) ok = ok && (in_sizes[i] == expect[i]);
  }
  // ws layout (bytes):
  //   Qp     @ 0          :    55,296
  //   Qk     @ 55,296     :   995,328   [l][d][h]
  //   scores @ 1,050,624  : 1,769,472   [bl][t][h]
  //   attn   @ 2,820,096  : 1,769,472   [bl][t][h]
  //   VAp    @ 4,589,568  : 31,850,496  [tq][bl][h][d]
  //   psum   @ 36,440,064 : 1,769,472   [dz][bl][f]
  //   NEED = 38,209,536
  const size_t NEED = 38209536;
  ok = ok && (ws_size >= NEED);

  if (!ok) {
    zfill<<<dim3((out_size + 255) / 256), dim3(256), 0, stream>>>(out, out_size);
    return;
  }

  const float* Kin   = (const float*)d_in[0];
  const float* Vin   = (const float*)d_in[1];
  const float* query = (const float*)d_in[2];
  const float* Wq    = (const float*)d_in[3];
  const float* bq    = (const float*)d_in[4];
  const float* Wk    = (const float*)d_in[5];
  const float* Wv    = (const float*)d_in[7];
  const float* bvp   = (const float*)d_in[8];
  const float* Wo    = (const float*)d_in[9];
  const float* bo    = (const float*)d_in[10];
  // bk (d_in[6]) unused: constant over t, cancels in softmax exactly.

  char* ws = (char*)d_ws;
  float* Qpw     = (float*)(ws);
  float* Qkw     = (float*)(ws + 55296);
  float* scoresw = (float*)(ws + 1050624);
  float* attnw   = (float*)(ws + 2820096);
  float* VApw    = (float*)(ws + 4589568);
  float* psumw   = (float*)(ws + 36440064);

  qproj    <<<dim3(27, 8),    dim3(256), 0, stream>>>(query, Wq, bq, Qpw);
  qk_mat   <<<dim3(3888),     dim3(256), 0, stream>>>(Qpw, Wk, Qkw);
  score_k  <<<dim3(216, 4),   dim3(256), 0, stream>>>(Kin, Qkw, scoresw);
  softmax_k<<<dim3(216),      dim3(256), 0, stream>>>(scoresw, attnw);
  va_k     <<<dim3(216, 4),   dim3(576), 0, stream>>>(Vin, attnw, VApw);
  pv_mat   <<<dim3(27, 8, 4), dim3(512), 0, stream>>>(VApw, Wv, psumw);
  out_gemm <<<dim3(27, 8),    dim3(256), 0, stream>>>(psumw, bvp, Wo, bo, out);
}

// Round 14
// 344.596 us; speedup vs baseline: 1.0512x; 1.0512x over previous
//
#include <hip/hip_runtime.h>
#include <stdint.h>

// ---- dims ----
// B=8, L=27, T=256, D=1152, GS=3, G=9, DD=512, H=8, HD=64, NQ=1, OD=2048
// Output dtype: FLOAT32 (verified round 4).
//
// Round 14: r12 base (312us, known-good) + two precedented changes:
//   score_sm_k: r12 score_k access pattern, 1024-thr block, psc via LDS,
//               softmax fused in-block -> attn directly (kills psc buffer
//               + softmax_k launch).
//   va_k      : float2 loads (G13), single pass, direct VA (NO partials --
//               r13's partials regressed).
// pv_mat / out_gemm / qproj / qk_mat: byte-identical to r12.
// Algebra (verified r9-r13): scores = K·Qk (bk cancels in softmax);
// pooled = (attn·V)·Wv + bv. All f32.

// ---------------------------------------------------------------------------
// K1: Qp[l,f] = (query[l,:] @ Wq[g] + bq[g]) * 0.125
// grid (27,8), block 256.
// ---------------------------------------------------------------------------
__global__ __launch_bounds__(256) void qproj(
    const float* __restrict__ query, const float* __restrict__ Wq,
    const float* __restrict__ bq, float* __restrict__ Qp)
{
  const int l = blockIdx.x, g = l / 3;
  const int fb = blockIdx.y * 64;
  __shared__ float q[1152];
  __shared__ float part[4][64];
  for (int i = threadIdx.x; i < 1152; i += 256) q[i] = query[(size_t)l * 1152 + i];
  __syncthreads();
  const int fi = threadIdx.x & 63;
  const int kq = threadIdx.x >> 6;            // 0..3, 288 d's each
  const float* W = Wq + (size_t)g * 1152 * 512 + fb + fi;
  float a0 = 0.f, a1 = 0.f;
  const int d0 = kq * 288;
#pragma unroll 4
  for (int d = d0; d < d0 + 288; d += 2) {
    a0 += q[d]     * W[(size_t)d * 512];
    a1 += q[d + 1] * W[(size_t)(d + 1) * 512];
  }
  part[kq][fi] = a0 + a1;
  __syncthreads();
  if (threadIdx.x < 64) {
    const int f = fb + threadIdx.x;
    float r = part[0][threadIdx.x] + part[1][threadIdx.x]
            + part[2][threadIdx.x] + part[3][threadIdx.x];
    Qp[l * 512 + f] = (r + bq[g * 512 + f]) * 0.125f;
  }
}

// ---------------------------------------------------------------------------
// K2: Qk[l,d,h] = sum_e Qp[l,h*64+e] * Wk[g,d,h*64+e]    (layout [l][d][h])
// grid 3888, block 256: 4 threads per (l,h,d), 2-level shuffle reduce.
// ---------------------------------------------------------------------------
__global__ __launch_bounds__(256) void qk_mat(
    const float* __restrict__ Qp, const float* __restrict__ Wk,
    float* __restrict__ Qk)
{
  const int gidx = blockIdx.x * 256 + threadIdx.x;  // 0..995327
  const int eg   = gidx & 3;
  const int item = gidx >> 2;         // 0..248831 = (l,h,d)
  const int l    = item / 9216;
  const int rem  = item % 9216;
  const int h    = rem / 1152;
  const int d    = rem % 1152;
  const int g    = l / 3;
  const float4* q4 = (const float4*)(Qp + l * 512 + h * 64 + eg * 16);
  const float4* w4 = (const float4*)(Wk + (size_t)g * 1152 * 512 + (size_t)d * 512 + h * 64 + eg * 16);
  float acc = 0.f;
#pragma unroll
  for (int e = 0; e < 4; e++) {
    const float4 a = q4[e], b = w4[e];
    acc += a.x * b.x + a.y * b.y + a.z * b.z + a.w * b.w;
  }
  acc += __shfl_xor(acc, 1, 64);
  acc += __shfl_xor(acc, 2, 64);
  if (eg == 0) Qk[((size_t)l * 1152 + d) * 8 + h] = acc;
}

// ---------------------------------------------------------------------------
// K3: fused scores+softmax -> attn[bl][t][h].  grid 216, block 1024.
// thread = (t = tid&255, dq = tid>>8): K row-stream over d-quarter (r12
// access pattern: 64 rows x 128B lines stay L1-resident), psc via LDS,
// threads<256 reduce + butterfly softmax (r12 softmax_k arithmetic).
// ---------------------------------------------------------------------------
__global__ __launch_bounds__(1024) void score_sm_k(
    const float* __restrict__ K, const float* __restrict__ Qk,
    float* __restrict__ attn)
{
  const int bl = blockIdx.x;          // 0..215
  const int l = bl % 27;
  const int tid = threadIdx.x;
  const int t  = tid & 255;           // token
  const int dq = tid >> 8;            // 0..3 (d-quarter of 288)

  __shared__ float psc[4][256][8];    // 32 KB
  __shared__ float red[4][8], red2[4][8];

  {
    const float4* Kr = (const float4*)(K + ((size_t)bl * 256 + t) * 1152 + dq * 288);
    const float* qk = Qk + ((size_t)l * 1152 + dq * 288) * 8;   // uniform
    float sc[8] = {0.f, 0.f, 0.f, 0.f, 0.f, 0.f, 0.f, 0.f};
#pragma unroll 2
    for (int i = 0; i < 72; i++) {
      const float4 kv = Kr[i];
      const float* q0 = qk + (i * 4) * 8;
#pragma unroll
      for (int h = 0; h < 8; h++) {
        sc[h] = fmaf(kv.x, q0[h],      sc[h]);
        sc[h] = fmaf(kv.y, q0[8 + h],  sc[h]);
        sc[h] = fmaf(kv.z, q0[16 + h], sc[h]);
        sc[h] = fmaf(kv.w, q0[24 + h], sc[h]);
      }
    }
#pragma unroll
    for (int h = 0; h < 8; h++) psc[dq][t][h] = sc[h];
  }
  __syncthreads();

  const int wid = tid >> 6, lane = tid & 63;
  float sc[8], p[8];
  if (tid < 256) {
#pragma unroll
    for (int h = 0; h < 8; h++)
      sc[h] = (psc[0][tid][h] + psc[1][tid][h]) + (psc[2][tid][h] + psc[3][tid][h]);
#pragma unroll
    for (int h = 0; h < 8; h++) {
      float m = sc[h];
#pragma unroll
      for (int o = 1; o < 64; o <<= 1) m = fmaxf(m, __shfl_xor(m, o, 64));
      if (lane == 0) red[wid][h] = m;
    }
  }
  __syncthreads();
  if (tid < 256) {
#pragma unroll
    for (int h = 0; h < 8; h++) {
      const float M = fmaxf(fmaxf(red[0][h], red[1][h]), fmaxf(red[2][h], red[3][h]));
      p[h] = __expf(sc[h] - M);
      float s = p[h];
#pragma unroll
      for (int o = 1; o < 64; o <<= 1) s += __shfl_xor(s, o, 64);
      if (lane == 0) red2[wid][h] = s;
    }
  }
  __syncthreads();
  if (tid < 256) {
    float* dst = attn + ((size_t)bl * 256 + tid) * 8;
#pragma unroll
    for (int h = 0; h < 8; h++) {
      const float S = red2[0][h] + red2[1][h] + red2[2][h] + red2[3][h];
      dst[h] = p[h] * (1.0f / S);
    }
  }
}

// ---------------------------------------------------------------------------
// K4: VA[bl][h][d] = sum_t attn[bl][t][h] * V[bl,t,d]
// grid 216, block 576 (9 waves; d = w*128 + lane*2, float2 coalesced).
// attn via wave-uniform s_loads. No LDS, no partials.
// ---------------------------------------------------------------------------
__global__ __launch_bounds__(576) void va_k(
    const float* __restrict__ V, const float* __restrict__ attn,
    float* __restrict__ VA)
{
  const int bl = blockIdx.x;          // 0..215
  const int w = threadIdx.x >> 6, lane = threadIdx.x & 63;
  const int d = w * 128 + lane * 2;   // 0..1150

  const float* Vbase = V + (size_t)bl * 256 * 1152 + d;
  const float* ab = attn + (size_t)bl * 256 * 8;   // uniform

  float2 acc[8];
#pragma unroll
  for (int h = 0; h < 8; h++) acc[h] = make_float2(0.f, 0.f);

#pragma unroll 4
  for (int t = 0; t < 256; t++) {
    const float2 v = *(const float2*)(Vbase + (size_t)t * 1152);
    const float* av = ab + t * 8;     // uniform -> s_load_dwordx8
#pragma unroll
    for (int h = 0; h < 8; h++) {
      acc[h].x = fmaf(av[h], v.x, acc[h].x);
      acc[h].y = fmaf(av[h], v.y, acc[h].y);
    }
  }
  float* dst = VA + (size_t)bl * 8 * 1152 + d;
#pragma unroll
  for (int h = 0; h < 8; h++)
    *(float2*)(dst + (size_t)h * 1152) = acc[h];
}

// ---------------------------------------------------------------------------
// K5: psum[dz][bl][e*8+h] = sum_{d in quarter dz} VA[bl,h,d]*Wv[g,d,h*64+e]
// grid (27,8,4) = (l,h,dz); block 512 = 8 waves (wave = b), lane = e.
// ---------------------------------------------------------------------------
__global__ __launch_bounds__(512) void pv_mat(
    const float* __restrict__ VA, const float* __restrict__ Wv,
    float* __restrict__ psum)
{
  const int l = blockIdx.x, g = l / 3, h = blockIdx.y, dz = blockIdx.z;
  const int b = threadIdx.x >> 6, lane = threadIdx.x & 63;
  const int bl = b * 27 + l;
  const float* W = Wv + (size_t)g * 1152 * 512 + h * 64 + lane;
  const float* va = VA + ((size_t)bl * 8 + h) * 1152;   // wave-uniform
  const int d0 = dz * 288;
  float a0 = 0.f, a1 = 0.f, a2 = 0.f, a3 = 0.f;
#pragma unroll 2
  for (int d = d0; d < d0 + 288; d += 4) {
    a0 = fmaf(va[d],     W[(size_t)(d)     * 512], a0);
    a1 = fmaf(va[d + 1], W[(size_t)(d + 1) * 512], a1);
    a2 = fmaf(va[d + 2], W[(size_t)(d + 2) * 512], a2);
    a3 = fmaf(va[d + 3], W[(size_t)(d + 3) * 512], a3);
  }
  psum[((size_t)dz * 216 + bl) * 512 + lane * 8 + h] = (a0 + a1) + (a2 + a3);
}

// ---------------------------------------------------------------------------
// K6: out[bl,n] = pooled[bl,:]@Wo[g] + bo[g];  pooled = sum_dz psum + bv_perm
// grid (27,8), block 256.
// ---------------------------------------------------------------------------
__global__ __launch_bounds__(256) void out_gemm(
    const float* __restrict__ psum, const float* __restrict__ bv,
    const float* __restrict__ Wo, const float* __restrict__ bo,
    float* __restrict__ out)
{
  const int l = blockIdx.x, g = l / 3;
  const int n = blockIdx.y * 256 + threadIdx.x;
  __shared__ float pl[8][512];
  for (int i = threadIdx.x; i < 4096; i += 256) {
    const int b = i >> 9, f = i & 511;
    const int bl = b * 27 + l;
    const int e = f >> 3, h = f & 7;           // f = e*8 + h
    float v = bv[g * 512 + h * 64 + e];
#pragma unroll
    for (int dz = 0; dz < 4; dz++)
      v += psum[((size_t)dz * 216 + bl) * 512 + f];
    pl[b][f] = v;
  }
  __syncthreads();
  const float* W = Wo + (size_t)g * 512 * 2048 + n;
  float acc[8] = {0.f, 0.f, 0.f, 0.f, 0.f, 0.f, 0.f, 0.f};
#pragma unroll 4
  for (int f = 0; f < 512; f++) {
    const float w = W[(size_t)f * 2048];
#pragma unroll
    for (int b = 0; b < 8; b++) acc[b] += pl[b][f] * w;
  }
  const float bb = bo[g * 2048 + n];
#pragma unroll
  for (int b = 0; b < 8; b++)
    out[(size_t)(b * 27 + l) * 2048 + n] = acc[b] + bb;
}

// ---------------------------------------------------------------------------
// sentinel: zero-fill f32 output (absmax would read ~1.06e-1 = max|ref|)
// ---------------------------------------------------------------------------
__global__ __launch_bounds__(256) void zfill(float* __restrict__ out, int n) {
  const int i = blockIdx.x * 256 + threadIdx.x;
  if (i < n) out[i] = 0.f;
}

// ---------------------------------------------------------------------------
extern "C" void kernel_launch(void* const* d_in, const int* in_sizes, int n_in,
                              void* d_out, int out_size, void* d_ws, size_t ws_size,
                              hipStream_t stream)
{
  float* out = (float*)d_out;   // f32 output (verified round 4)

  // ---- config guards ----
  bool ok = (n_in == 11) && (out_size == 8 * 27 * 2048);
  if (ok) {
    const int expect[11] = {
      8 * 27 * 256 * 1152,  // K
      8 * 27 * 256 * 1152,  // V
      27 * 1 * 1152,        // query
      9 * 1152 * 512,       // Wq
      9 * 512,              // bq
      9 * 1152 * 512,       // Wk
      9 * 512,              // bk
      9 * 1152 * 512,       // Wv
      9 * 512,              // bv
      9 * 512 * 2048,       // Wo
      9 * 2048              // bo
    };
    for (int i = 0; i < 11; i++) ok = ok && (in_sizes[i] == expect[i]);
  }
  // ws layout (bytes):
  //   Qp   @ 0          :    55,296
  //   Qk   @ 55,296     :   995,328   [l][d][h]
  //   attn @ 1,050,624  : 1,769,472   [bl][t][h]
  //   VA   @ 2,820,096  : 7,962,624   [bl][h][d]
  //   psum @ 10,782,720 : 1,769,472   [dz][bl][f]
  //   NEED = 12,552,192
  const size_t NEED = 12552192;
  ok = ok && (ws_size >= NEED);

  if (!ok) {
    zfill<<<dim3((out_size + 255) / 256), dim3(256), 0, stream>>>(out, out_size);
    return;
  }

  const float* Kin   = (const float*)d_in[0];
  const float* Vin   = (const float*)d_in[1];
  const float* query = (const float*)d_in[2];
  const float* Wq    = (const float*)d_in[3];
  const float* bq    = (const float*)d_in[4];
  const float* Wk    = (const float*)d_in[5];
  const float* Wv    = (const float*)d_in[7];
  const float* bvp   = (const float*)d_in[8];
  const float* Wo    = (const float*)d_in[9];
  const float* bo    = (const float*)d_in[10];
  // bk (d_in[6]) unused: constant over t, cancels in softmax exactly.

  char* ws = (char*)d_ws;
  float* Qpw   = (float*)(ws);
  float* Qkw   = (float*)(ws + 55296);
  float* attnw = (float*)(ws + 1050624);
  float* VAw   = (float*)(ws + 2820096);
  float* psumw = (float*)(ws + 10782720);

  qproj     <<<dim3(27, 8),    dim3(256),  0, stream>>>(query, Wq, bq, Qpw);
  qk_mat    <<<dim3(3888),     dim3(256),  0, stream>>>(Qpw, Wk, Qkw);
  score_sm_k<<<dim3(216),      dim3(1024), 0, stream>>>(Kin, Qkw, attnw);
  va_k      <<<dim3(216),      dim3(576),  0, stream>>>(Vin, attnw, VAw);
  pv_mat    <<<dim3(27, 8, 4), dim3(512),  0, stream>>>(VAw, Wv, psumw);
  out_gemm  <<<dim3(27, 8),    dim3(256),  0, stream>>>(psumw, bvp, Wo, bo, out);
}

// Round 15
// 320.861 us; speedup vs baseline: 1.1290x; 1.0740x over previous
//
#include <hip/hip_runtime.h>
#include <stdint.h>

// ---- dims ----
// B=8, L=27, T=256, D=1152, GS=3, G=9, DD=512, H=8, HD=64, NQ=1, OD=2048
// Output dtype: FLOAT32 (verified round 4).
//
// Round 15: r12 baseline (312us) + ONE change: score path swapped to the
// r13 LDS-staged coalesced score_k (fixes the L1-thrashing per-lane K
// row-stream measured at 160us / 12.6% hbm / 5% VALU in r14).
// All other kernels verbatim r12.
// Algebra (verified r9-r14): scores = K·Qk (bk cancels in softmax);
// pooled = (attn·V)·Wv + bv. All f32.

// ---------------------------------------------------------------------------
// K1: Qp[l,f] = (query[l,:] @ Wq[g] + bq[g]) * 0.125
// grid (27,8), block 256.
// ---------------------------------------------------------------------------
__global__ __launch_bounds__(256) void qproj(
    const float* __restrict__ query, const float* __restrict__ Wq,
    const float* __restrict__ bq, float* __restrict__ Qp)
{
  const int l = blockIdx.x, g = l / 3;
  const int fb = blockIdx.y * 64;
  __shared__ float q[1152];
  __shared__ float part[4][64];
  for (int i = threadIdx.x; i < 1152; i += 256) q[i] = query[(size_t)l * 1152 + i];
  __syncthreads();
  const int fi = threadIdx.x & 63;
  const int kq = threadIdx.x >> 6;            // 0..3, 288 d's each
  const float* W = Wq + (size_t)g * 1152 * 512 + fb + fi;
  float a0 = 0.f, a1 = 0.f;
  const int d0 = kq * 288;
#pragma unroll 4
  for (int d = d0; d < d0 + 288; d += 2) {
    a0 += q[d]     * W[(size_t)d * 512];
    a1 += q[d + 1] * W[(size_t)(d + 1) * 512];
  }
  part[kq][fi] = a0 + a1;
  __syncthreads();
  if (threadIdx.x < 64) {
    const int f = fb + threadIdx.x;
    float r = part[0][threadIdx.x] + part[1][threadIdx.x]
            + part[2][threadIdx.x] + part[3][threadIdx.x];
    Qp[l * 512 + f] = (r + bq[g * 512 + f]) * 0.125f;
  }
}

// ---------------------------------------------------------------------------
// K2: Qk[l,d,h] = sum_e Qp[l,h*64+e] * Wk[g,d,h*64+e]    (layout [l][d][h])
// grid 3888, block 256: 4 threads per (l,h,d), 2-level shuffle reduce.
// ---------------------------------------------------------------------------
__global__ __launch_bounds__(256) void qk_mat(
    const float* __restrict__ Qp, const float* __restrict__ Wk,
    float* __restrict__ Qk)
{
  const int gidx = blockIdx.x * 256 + threadIdx.x;  // 0..995327
  const int eg   = gidx & 3;
  const int item = gidx >> 2;         // 0..248831 = (l,h,d)
  const int l    = item / 9216;
  const int rem  = item % 9216;
  const int h    = rem / 1152;
  const int d    = rem % 1152;
  const int g    = l / 3;
  const float4* q4 = (const float4*)(Qp + l * 512 + h * 64 + eg * 16);
  const float4* w4 = (const float4*)(Wk + (size_t)g * 1152 * 512 + (size_t)d * 512 + h * 64 + eg * 16);
  float acc = 0.f;
#pragma unroll
  for (int e = 0; e < 4; e++) {
    const float4 a = q4[e], b = w4[e];
    acc += a.x * b.x + a.y * b.y + a.z * b.z + a.w * b.w;
  }
  acc += __shfl_xor(acc, 1, 64);
  acc += __shfl_xor(acc, 2, 64);
  if (eg == 0) Qk[((size_t)l * 1152 + d) * 8 + h] = acc;
}

// ---------------------------------------------------------------------------
// K3a: scores[bl][t][h] = sum_d K[bl,t,d] * Qk[l,d,h]
// grid (216,4 token-tiles), block 256 = (tt 64 tokens x ds 4 d-quarters).
// 6 chunks of 192 d: coalesced float4 K loads -> LDS[64][195] (195%32=3 ->
// column reads 2 lanes/bank = free) -> scalar compute with wave-uniform Qk
// s_loads. In-block ds-reduce writes final scores.  [verbatim r13]
// ---------------------------------------------------------------------------
__global__ __launch_bounds__(256) void score_k(
    const float* __restrict__ K, const float* __restrict__ Qk,
    float* __restrict__ scores)
{
  const int bl = blockIdx.x;          // 0..215
  const int tq = blockIdx.y;          // 0..3 (64-token tile)
  const int l = bl % 27;
  const int tid = threadIdx.x;
  const int tt = tid & 63;            // token within tile
  const int ds = tid >> 6;            // d-subchunk (48 floats of each 192)

  __shared__ float lds[64 * 195];     // 49,920 B; also reused for reduce

  const float* Kbase = K + ((size_t)bl * 256 + tq * 64) * 1152;
  const float* qkl = Qk + (size_t)l * 1152 * 8;

  float sc[8] = {0.f, 0.f, 0.f, 0.f, 0.f, 0.f, 0.f, 0.f};

  for (int dc = 0; dc < 6; dc++) {
    __syncthreads();                  // protect lds from previous reads
    // stage: 64 rows x 192 floats = 3072 float4; 12 iters x 256 threads
#pragma unroll
    for (int it = 0; it < 12; it++) {
      const int flat = it * 256 + tid;       // float4 slot
      const int row = flat / 48, col = flat % 48;
      const float4 v = *(const float4*)(Kbase + (size_t)row * 1152 + dc * 192 + col * 4);
      float* p = &lds[row * 195 + col * 4];
      p[0] = v.x; p[1] = v.y; p[2] = v.z; p[3] = v.w;
    }
    __syncthreads();
    const float* q0 = qkl + (size_t)(dc * 192 + ds * 48) * 8;  // wave-uniform
    const float* krow = &lds[tt * 195 + ds * 48];
#pragma unroll 6
    for (int j = 0; j < 48; j++) {
      const float kv = krow[j];
      const float* q = q0 + j * 8;
#pragma unroll
      for (int h = 0; h < 8; h++) sc[h] = fmaf(kv, q[h], sc[h]);
    }
  }

  // reduce the 4 ds-partials per (tt, h) via LDS
  __syncthreads();
#pragma unroll
  for (int h = 0; h < 8; h++) lds[(ds * 64 + tt) * 8 + h] = sc[h];
  __syncthreads();
  if (tid < 64) {
    float* dst = scores + ((size_t)bl * 256 + tq * 64 + tid) * 8;
#pragma unroll
    for (int h = 0; h < 8; h++)
      dst[h] = (lds[(0 * 64 + tid) * 8 + h] + lds[(1 * 64 + tid) * 8 + h])
             + (lds[(2 * 64 + tid) * 8 + h] + lds[(3 * 64 + tid) * 8 + h]);
  }
}

// ---------------------------------------------------------------------------
// K3b: softmax over 256 tokens per (bl,h). grid 216, block 256 (thread = t).
// attn[bl][t][h].
// ---------------------------------------------------------------------------
__global__ __launch_bounds__(256) void softmax_k(
    const float* __restrict__ scores, float* __restrict__ attn)
{
  const int bl = blockIdx.x;
  const int t = threadIdx.x;
  const int wid = t >> 6, lane = t & 63;
  __shared__ float red[4][8], red2[4][8];

  float sc[8];
  const float* src = scores + ((size_t)bl * 256 + t) * 8;
#pragma unroll
  for (int h = 0; h < 8; h++) sc[h] = src[h];
#pragma unroll
  for (int h = 0; h < 8; h++) {
    float m = sc[h];
#pragma unroll
    for (int o = 1; o < 64; o <<= 1) m = fmaxf(m, __shfl_xor(m, o, 64));
    if (lane == 0) red[wid][h] = m;
  }
  __syncthreads();
  float p[8];
#pragma unroll
  for (int h = 0; h < 8; h++) {
    const float M = fmaxf(fmaxf(red[0][h], red[1][h]), fmaxf(red[2][h], red[3][h]));
    p[h] = __expf(sc[h] - M);
    float s = p[h];
#pragma unroll
    for (int o = 1; o < 64; o <<= 1) s += __shfl_xor(s, o, 64);
    if (lane == 0) red2[wid][h] = s;
  }
  __syncthreads();
  float* dst = attn + ((size_t)bl * 256 + t) * 8;
#pragma unroll
  for (int h = 0; h < 8; h++) {
    const float S = red2[0][h] + red2[1][h] + red2[2][h] + red2[3][h];
    dst[h] = p[h] * (1.0f / S);
  }
}

// ---------------------------------------------------------------------------
// K3c: VA[bl][h][d] = sum_t attn[bl][t][h] * V[bl,t,d]
// grid (216, 3), block 384 (thread = d-element within third). No LDS.
// V coalesced; attn via wave-uniform s_load.  [verbatim r12]
// ---------------------------------------------------------------------------
__global__ __launch_bounds__(384) void va_k(
    const float* __restrict__ V, const float* __restrict__ attn,
    float* __restrict__ VA)
{
  const int bl = blockIdx.x;          // 0..215
  const int dt = blockIdx.y;          // 0..2 (d-third of 384)
  const int d  = dt * 384 + threadIdx.x;

  const float* Vbase = V + (size_t)bl * 256 * 1152 + d;
  const float* ab = attn + (size_t)bl * 256 * 8;   // uniform

  float acc[8] = {0.f, 0.f, 0.f, 0.f, 0.f, 0.f, 0.f, 0.f};
#pragma unroll 4
  for (int t = 0; t < 256; t++) {
    const float v = Vbase[(size_t)t * 1152];
    const float* av = ab + t * 8;     // uniform -> s_load_dwordx8
#pragma unroll
    for (int h = 0; h < 8; h++) acc[h] = fmaf(av[h], v, acc[h]);
  }
  float* dst = VA + (size_t)bl * 8 * 1152 + d;
#pragma unroll
  for (int h = 0; h < 8; h++) dst[(size_t)h * 1152] = acc[h];
}

// ---------------------------------------------------------------------------
// K4: psum[dz][bl][e*8+h] = sum_{d in quarter dz} VA[bl,h,d]*Wv[g,d,h*64+e]
// grid (27,8,4) = (l,h,dz); block 512 = 8 waves (wave = b), lane = e.
// ---------------------------------------------------------------------------
__global__ __launch_bounds__(512) void pv_mat(
    const float* __restrict__ VA, const float* __restrict__ Wv,
    float* __restrict__ psum)
{
  const int l = blockIdx.x, g = l / 3, h = blockIdx.y, dz = blockIdx.z;
  const int b = threadIdx.x >> 6, lane = threadIdx.x & 63;
  const int bl = b * 27 + l;
  const float* W = Wv + (size_t)g * 1152 * 512 + h * 64 + lane;
  const float* va = VA + ((size_t)bl * 8 + h) * 1152;   // wave-uniform
  const int d0 = dz * 288;
  float a0 = 0.f, a1 = 0.f, a2 = 0.f, a3 = 0.f;
#pragma unroll 2
  for (int d = d0; d < d0 + 288; d += 4) {
    a0 = fmaf(va[d],     W[(size_t)(d)     * 512], a0);
    a1 = fmaf(va[d + 1], W[(size_t)(d + 1) * 512], a1);
    a2 = fmaf(va[d + 2], W[(size_t)(d + 2) * 512], a2);
    a3 = fmaf(va[d + 3], W[(size_t)(d + 3) * 512], a3);
  }
  psum[((size_t)dz * 216 + bl) * 512 + lane * 8 + h] = (a0 + a1) + (a2 + a3);
}

// ---------------------------------------------------------------------------
// K5: out[bl,n] = pooled[bl,:]@Wo[g] + bo[g];  pooled = sum_dz psum + bv_perm
// grid (27,8), block 256.
// ---------------------------------------------------------------------------
__global__ __launch_bounds__(256) void out_gemm(
    const float* __restrict__ psum, const float* __restrict__ bv,
    const float* __restrict__ Wo, const float* __restrict__ bo,
    float* __restrict__ out)
{
  const int l = blockIdx.x, g = l / 3;
  const int n = blockIdx.y * 256 + threadIdx.x;
  __shared__ float pl[8][512];
  for (int i = threadIdx.x; i < 4096; i += 256) {
    const int b = i >> 9, f = i & 511;
    const int bl = b * 27 + l;
    const int e = f >> 3, h = f & 7;           // f = e*8 + h
    float v = bv[g * 512 + h * 64 + e];
#pragma unroll
    for (int dz = 0; dz < 4; dz++)
      v += psum[((size_t)dz * 216 + bl) * 512 + f];
    pl[b][f] = v;
  }
  __syncthreads();
  const float* W = Wo + (size_t)g * 512 * 2048 + n;
  float acc[8] = {0.f, 0.f, 0.f, 0.f, 0.f, 0.f, 0.f, 0.f};
#pragma unroll 4
  for (int f = 0; f < 512; f++) {
    const float w = W[(size_t)f * 2048];
#pragma unroll
    for (int b = 0; b < 8; b++) acc[b] += pl[b][f] * w;
  }
  const float bb = bo[g * 2048 + n];
#pragma unroll
  for (int b = 0; b < 8; b++)
    out[(size_t)(b * 27 + l) * 2048 + n] = acc[b] + bb;
}

// ---------------------------------------------------------------------------
// sentinel: zero-fill f32 output (absmax would read ~1.06e-1 = max|ref|)
// ---------------------------------------------------------------------------
__global__ __launch_bounds__(256) void zfill(float* __restrict__ out, int n) {
  const int i = blockIdx.x * 256 + threadIdx.x;
  if (i < n) out[i] = 0.f;
}

// ---------------------------------------------------------------------------
extern "C" void kernel_launch(void* const* d_in, const int* in_sizes, int n_in,
                              void* d_out, int out_size, void* d_ws, size_t ws_size,
                              hipStream_t stream)
{
  float* out = (float*)d_out;   // f32 output (verified round 4)

  // ---- config guards ----
  bool ok = (n_in == 11) && (out_size == 8 * 27 * 2048);
  if (ok) {
    const int expect[11] = {
      8 * 27 * 256 * 1152,  // K
      8 * 27 * 256 * 1152,  // V
      27 * 1 * 1152,        // query
      9 * 1152 * 512,       // Wq
      9 * 512,              // bq
      9 * 1152 * 512,       // Wk
      9 * 512,              // bk
      9 * 1152 * 512,       // Wv
      9 * 512,              // bv
      9 * 512 * 2048,       // Wo
      9 * 2048              // bo
    };
    for (int i = 0; i < 11; i++) ok = ok && (in_sizes[i] == expect[i]);
  }
  // ws layout (bytes):
  //   Qp     @ 0          :    55,296
  //   Qk     @ 55,296     :   995,328   [l][d][h]
  //   scores @ 1,050,624  : 1,769,472   [bl][t][h]
  //   attn   @ 2,820,096  : 1,769,472   [bl][t][h]
  //   VA     @ 4,589,568  : 7,962,624   [bl][h][d]
  //   psum   @ 12,552,192 : 1,769,472   [dz][bl][f]
  //   NEED = 14,321,664
  const size_t NEED = 14321664;
  ok = ok && (ws_size >= NEED);

  if (!ok) {
    zfill<<<dim3((out_size + 255) / 256), dim3(256), 0, stream>>>(out, out_size);
    return;
  }

  const float* Kin   = (const float*)d_in[0];
  const float* Vin   = (const float*)d_in[1];
  const float* query = (const float*)d_in[2];
  const float* Wq    = (const float*)d_in[3];
  const float* bq    = (const float*)d_in[4];
  const float* Wk    = (const float*)d_in[5];
  const float* Wv    = (const float*)d_in[7];
  const float* bvp   = (const float*)d_in[8];
  const float* Wo    = (const float*)d_in[9];
  const float* bo    = (const float*)d_in[10];
  // bk (d_in[6]) unused: constant over t, cancels in softmax exactly.

  char* ws = (char*)d_ws;
  float* Qpw     = (float*)(ws);
  float* Qkw     = (float*)(ws + 55296);
  float* scoresw = (float*)(ws + 1050624);
  float* attnw   = (float*)(ws + 2820096);
  float* VAw     = (float*)(ws + 4589568);
  float* psumw   = (float*)(ws + 12552192);

  qproj    <<<dim3(27, 8),    dim3(256), 0, stream>>>(query, Wq, bq, Qpw);
  qk_mat   <<<dim3(3888),     dim3(256), 0, stream>>>(Qpw, Wk, Qkw);
  score_k  <<<dim3(216, 4),   dim3(256), 0, stream>>>(Kin, Qkw, scoresw);
  softmax_k<<<dim3(216),      dim3(256), 0, stream>>>(scoresw, attnw);
  va_k     <<<dim3(216, 3),   dim3(384), 0, stream>>>(Vin, attnw, VAw);
  pv_mat   <<<dim3(27, 8, 4), dim3(512), 0, stream>>>(VAw, Wv, psumw);
  out_gemm <<<dim3(27, 8),    dim3(256), 0, stream>>>(psumw, bvp, Wo, bo, out);
}

// Round 16
// 279.468 us; speedup vs baseline: 1.2962x; 1.1481x over previous
//
#include <hip/hip_runtime.h>
#include <stdint.h>

// ---- dims ----
// B=8, L=27, T=256, D=1152, GS=3, G=9, DD=512, H=8, HD=64, NQ=1, OD=2048
// Output dtype: FLOAT32 (verified round 4).
//
// Round 16: register-blocked score_k (ONLY kernel changed vs r15).
// Diagnosis r12/r14/r15: score path ~144-160us with hbm 12%, VALU 6% --
// operand-supply bound: 8 tiny Qk loads per K element (s_load/SMEM mixes
// with DS in lgkmcnt -> serializing interlocks). Fix: thread owns
// (4 tokens x 8 heads x 12-d slice); q[12][8] and kv[12] hoisted to VGPRs
// via ds_read_b128; inner loop = 384 register-only FMAs (no SMEM).
// Algebra (verified r9-r15): scores = K·Qk (bk cancels in softmax);
// pooled = (attn·V)·Wv + bv. All f32.

// ---------------------------------------------------------------------------
// K1: Qp[l,f] = (query[l,:] @ Wq[g] + bq[g]) * 0.125
// grid (27,8), block 256.
// ---------------------------------------------------------------------------
__global__ __launch_bounds__(256) void qproj(
    const float* __restrict__ query, const float* __restrict__ Wq,
    const float* __restrict__ bq, float* __restrict__ Qp)
{
  const int l = blockIdx.x, g = l / 3;
  const int fb = blockIdx.y * 64;
  __shared__ float q[1152];
  __shared__ float part[4][64];
  for (int i = threadIdx.x; i < 1152; i += 256) q[i] = query[(size_t)l * 1152 + i];
  __syncthreads();
  const int fi = threadIdx.x & 63;
  const int kq = threadIdx.x >> 6;            // 0..3, 288 d's each
  const float* W = Wq + (size_t)g * 1152 * 512 + fb + fi;
  float a0 = 0.f, a1 = 0.f;
  const int d0 = kq * 288;
#pragma unroll 4
  for (int d = d0; d < d0 + 288; d += 2) {
    a0 += q[d]     * W[(size_t)d * 512];
    a1 += q[d + 1] * W[(size_t)(d + 1) * 512];
  }
  part[kq][fi] = a0 + a1;
  __syncthreads();
  if (threadIdx.x < 64) {
    const int f = fb + threadIdx.x;
    float r = part[0][threadIdx.x] + part[1][threadIdx.x]
            + part[2][threadIdx.x] + part[3][threadIdx.x];
    Qp[l * 512 + f] = (r + bq[g * 512 + f]) * 0.125f;
  }
}

// ---------------------------------------------------------------------------
// K2: Qk[l,d,h] = sum_e Qp[l,h*64+e] * Wk[g,d,h*64+e]    (layout [l][d][h])
// grid 3888, block 256: 4 threads per (l,h,d), 2-level shuffle reduce.
// ---------------------------------------------------------------------------
__global__ __launch_bounds__(256) void qk_mat(
    const float* __restrict__ Qp, const float* __restrict__ Wk,
    float* __restrict__ Qk)
{
  const int gidx = blockIdx.x * 256 + threadIdx.x;  // 0..995327
  const int eg   = gidx & 3;
  const int item = gidx >> 2;         // 0..248831 = (l,h,d)
  const int l    = item / 9216;
  const int rem  = item % 9216;
  const int h    = rem / 1152;
  const int d    = rem % 1152;
  const int g    = l / 3;
  const float4* q4 = (const float4*)(Qp + l * 512 + h * 64 + eg * 16);
  const float4* w4 = (const float4*)(Wk + (size_t)g * 1152 * 512 + (size_t)d * 512 + h * 64 + eg * 16);
  float acc = 0.f;
#pragma unroll
  for (int e = 0; e < 4; e++) {
    const float4 a = q4[e], b = w4[e];
    acc += a.x * b.x + a.y * b.y + a.z * b.z + a.w * b.w;
  }
  acc += __shfl_xor(acc, 1, 64);
  acc += __shfl_xor(acc, 2, 64);
  if (eg == 0) Qk[((size_t)l * 1152 + d) * 8 + h] = acc;
}

// ---------------------------------------------------------------------------
// K3a: scores[bl][t][h] = sum_d K[bl,t,d] * Qk[l,d,h]   (register-blocked)
// grid (216,4 token-tiles), block 256 = (tg 16 token-groups x dg 16 d-groups).
// Per 192-d chunk: stage K[64][192]->LDS(stride 196, b128-aligned), stage
// Qk chunk [192][8]->LDS; hoist q[12][8]+kv[12] to VGPRs (b128); 384
// register FMAs. dg-partials reduced via LDS (Kt reused).
// ---------------------------------------------------------------------------
__global__ __launch_bounds__(256) void score_k(
    const float* __restrict__ K, const float* __restrict__ Qk,
    float* __restrict__ scores)
{
  const int bl = blockIdx.x;          // 0..215
  const int tq = blockIdx.y;          // 0..3 (64-token tile)
  const int l = bl % 27;
  const int tid = threadIdx.x;
  const int tg = tid & 15;            // token group: tokens tg*4..+4
  const int dg = tid >> 4;            // d-slice: d = dg*12..+12 within chunk

  __shared__ __align__(16) float Kt[64 * 196];   // 50,176 B; reused for reduce
  __shared__ __align__(16) float Qs[192 * 8];    // 6,144 B

  const float* Kbase = K + ((size_t)bl * 256 + tq * 64) * 1152;
  const float* Qbase = Qk + (size_t)l * 1152 * 8;

  float acc[4][8];
#pragma unroll
  for (int tt = 0; tt < 4; tt++)
#pragma unroll
    for (int h = 0; h < 8; h++) acc[tt][h] = 0.f;

  for (int dc = 0; dc < 6; dc++) {
    __syncthreads();                  // protect LDS from previous reads
    // stage K tile: 64 rows x 192 floats = 3072 float4
#pragma unroll
    for (int it = 0; it < 12; it++) {
      const int flat = it * 256 + tid;
      const int row = flat / 48, col = flat % 48;
      const float4 v = *(const float4*)(Kbase + (size_t)row * 1152 + dc * 192 + col * 4);
      *(float4*)&Kt[row * 196 + col * 4] = v;
    }
    // stage Qk chunk: 192 d x 8 h = 1536 floats = 384 float4
    {
      const float4* qsrc = (const float4*)(Qbase + (size_t)dc * 192 * 8);
      *(float4*)&Qs[tid * 4] = qsrc[tid];
      if (tid < 128) *(float4*)&Qs[(256 + tid) * 4] = qsrc[256 + tid];
    }
    __syncthreads();

    // hoist q block: 12 d x 8 h -> VGPRs
    float q[12][8];
#pragma unroll
    for (int j = 0; j < 12; j++) {
      *(float4*)&q[j][0] = *(const float4*)&Qs[(dg * 12 + j) * 8];
      *(float4*)&q[j][4] = *(const float4*)&Qs[(dg * 12 + j) * 8 + 4];
    }
    // per token: hoist kv[12], then 96 register FMAs
#pragma unroll
    for (int tt = 0; tt < 4; tt++) {
      float kv[12];
      const float* kr = &Kt[(tg * 4 + tt) * 196 + dg * 12];
      *(float4*)&kv[0] = *(const float4*)(kr + 0);
      *(float4*)&kv[4] = *(const float4*)(kr + 4);
      *(float4*)&kv[8] = *(const float4*)(kr + 8);
#pragma unroll
      for (int j = 0; j < 12; j++)
#pragma unroll
        for (int h = 0; h < 8; h++)
          acc[tt][h] = fmaf(kv[j], q[j][h], acc[tt][h]);
    }
  }

  // reduce 16 dg-partials per (t,h): red[dg][t][h] overlaid on Kt
  __syncthreads();
#pragma unroll
  for (int tt = 0; tt < 4; tt++) {
    *(float4*)&Kt[(dg * 64 + tg * 4 + tt) * 8    ] = *(float4*)&acc[tt][0];
    *(float4*)&Kt[(dg * 64 + tg * 4 + tt) * 8 + 4] = *(float4*)&acc[tt][4];
  }
  __syncthreads();
  for (int out = tid; out < 512; out += 256) {
    const int t = out >> 3, h = out & 7;
    float s = 0.f;
#pragma unroll
    for (int dgi = 0; dgi < 16; dgi++) s += Kt[(dgi * 64 + t) * 8 + h];
    scores[((size_t)bl * 256 + tq * 64 + t) * 8 + h] = s;
  }
}

// ---------------------------------------------------------------------------
// K3b: softmax over 256 tokens per (bl,h). grid 216, block 256 (thread = t).
// attn[bl][t][h].
// ---------------------------------------------------------------------------
__global__ __launch_bounds__(256) void softmax_k(
    const float* __restrict__ scores, float* __restrict__ attn)
{
  const int bl = blockIdx.x;
  const int t = threadIdx.x;
  const int wid = t >> 6, lane = t & 63;
  __shared__ float red[4][8], red2[4][8];

  float sc[8];
  const float* src = scores + ((size_t)bl * 256 + t) * 8;
#pragma unroll
  for (int h = 0; h < 8; h++) sc[h] = src[h];
#pragma unroll
  for (int h = 0; h < 8; h++) {
    float m = sc[h];
#pragma unroll
    for (int o = 1; o < 64; o <<= 1) m = fmaxf(m, __shfl_xor(m, o, 64));
    if (lane == 0) red[wid][h] = m;
  }
  __syncthreads();
  float p[8];
#pragma unroll
  for (int h = 0; h < 8; h++) {
    const float M = fmaxf(fmaxf(red[0][h], red[1][h]), fmaxf(red[2][h], red[3][h]));
    p[h] = __expf(sc[h] - M);
    float s = p[h];
#pragma unroll
    for (int o = 1; o < 64; o <<= 1) s += __shfl_xor(s, o, 64);
    if (lane == 0) red2[wid][h] = s;
  }
  __syncthreads();
  float* dst = attn + ((size_t)bl * 256 + t) * 8;
#pragma unroll
  for (int h = 0; h < 8; h++) {
    const float S = red2[0][h] + red2[1][h] + red2[2][h] + red2[3][h];
    dst[h] = p[h] * (1.0f / S);
  }
}

// ---------------------------------------------------------------------------
// K3c: VA[bl][h][d] = sum_t attn[bl][t][h] * V[bl,t,d]
// grid (216, 3), block 384 (thread = d-element within third). No LDS.
// V coalesced; attn via wave-uniform s_load.  [verbatim r12]
// ---------------------------------------------------------------------------
__global__ __launch_bounds__(384) void va_k(
    const float* __restrict__ V, const float* __restrict__ attn,
    float* __restrict__ VA)
{
  const int bl = blockIdx.x;          // 0..215
  const int dt = blockIdx.y;          // 0..2 (d-third of 384)
  const int d  = dt * 384 + threadIdx.x;

  const float* Vbase = V + (size_t)bl * 256 * 1152 + d;
  const float* ab = attn + (size_t)bl * 256 * 8;   // uniform

  float acc[8] = {0.f, 0.f, 0.f, 0.f, 0.f, 0.f, 0.f, 0.f};
#pragma unroll 4
  for (int t = 0; t < 256; t++) {
    const float v = Vbase[(size_t)t * 1152];
    const float* av = ab + t * 8;     // uniform -> s_load_dwordx8
#pragma unroll
    for (int h = 0; h < 8; h++) acc[h] = fmaf(av[h], v, acc[h]);
  }
  float* dst = VA + (size_t)bl * 8 * 1152 + d;
#pragma unroll
  for (int h = 0; h < 8; h++) dst[(size_t)h * 1152] = acc[h];
}

// ---------------------------------------------------------------------------
// K4: psum[dz][bl][e*8+h] = sum_{d in quarter dz} VA[bl,h,d]*Wv[g,d,h*64+e]
// grid (27,8,4) = (l,h,dz); block 512 = 8 waves (wave = b), lane = e.
// ---------------------------------------------------------------------------
__global__ __launch_bounds__(512) void pv_mat(
    const float* __restrict__ VA, const float* __restrict__ Wv,
    float* __restrict__ psum)
{
  const int l = blockIdx.x, g = l / 3, h = blockIdx.y, dz = blockIdx.z;
  const int b = threadIdx.x >> 6, lane = threadIdx.x & 63;
  const int bl = b * 27 + l;
  const float* W = Wv + (size_t)g * 1152 * 512 + h * 64 + lane;
  const float* va = VA + ((size_t)bl * 8 + h) * 1152;   // wave-uniform
  const int d0 = dz * 288;
  float a0 = 0.f, a1 = 0.f, a2 = 0.f, a3 = 0.f;
#pragma unroll 2
  for (int d = d0; d < d0 + 288; d += 4) {
    a0 = fmaf(va[d],     W[(size_t)(d)     * 512], a0);
    a1 = fmaf(va[d + 1], W[(size_t)(d + 1) * 512], a1);
    a2 = fmaf(va[d + 2], W[(size_t)(d + 2) * 512], a2);
    a3 = fmaf(va[d + 3], W[(size_t)(d + 3) * 512], a3);
  }
  psum[((size_t)dz * 216 + bl) * 512 + lane * 8 + h] = (a0 + a1) + (a2 + a3);
}

// ---------------------------------------------------------------------------
// K5: out[bl,n] = pooled[bl,:]@Wo[g] + bo[g];  pooled = sum_dz psum + bv_perm
// grid (27,8), block 256.
// ---------------------------------------------------------------------------
__global__ __launch_bounds__(256) void out_gemm(
    const float* __restrict__ psum, const float* __restrict__ bv,
    const float* __restrict__ Wo, const float* __restrict__ bo,
    float* __restrict__ out)
{
  const int l = blockIdx.x, g = l / 3;
  const int n = blockIdx.y * 256 + threadIdx.x;
  __shared__ float pl[8][512];
  for (int i = threadIdx.x; i < 4096; i += 256) {
    const int b = i >> 9, f = i & 511;
    const int bl = b * 27 + l;
    const int e = f >> 3, h = f & 7;           // f = e*8 + h
    float v = bv[g * 512 + h * 64 + e];
#pragma unroll
    for (int dz = 0; dz < 4; dz++)
      v += psum[((size_t)dz * 216 + bl) * 512 + f];
    pl[b][f] = v;
  }
  __syncthreads();
  const float* W = Wo + (size_t)g * 512 * 2048 + n;
  float acc[8] = {0.f, 0.f, 0.f, 0.f, 0.f, 0.f, 0.f, 0.f};
#pragma unroll 4
  for (int f = 0; f < 512; f++) {
    const float w = W[(size_t)f * 2048];
#pragma unroll
    for (int b = 0; b < 8; b++) acc[b] += pl[b][f] * w;
  }
  const float bb = bo[g * 2048 + n];
#pragma unroll
  for (int b = 0; b < 8; b++)
    out[(size_t)(b * 27 + l) * 2048 + n] = acc[b] + bb;
}

// ---------------------------------------------------------------------------
// sentinel: zero-fill f32 output (absmax would read ~1.06e-1 = max|ref|)
// ---------------------------------------------------------------------------
__global__ __launch_bounds__(256) void zfill(float* __restrict__ out, int n) {
  const int i = blockIdx.x * 256 + threadIdx.x;
  if (i < n) out[i] = 0.f;
}

// ---------------------------------------------------------------------------
extern "C" void kernel_launch(void* const* d_in, const int* in_sizes, int n_in,
                              void* d_out, int out_size, void* d_ws, size_t ws_size,
                              hipStream_t stream)
{
  float* out = (float*)d_out;   // f32 output (verified round 4)

  // ---- config guards ----
  bool ok = (n_in == 11) && (out_size == 8 * 27 * 2048);
  if (ok) {
    const int expect[11] = {
      8 * 27 * 256 * 1152,  // K
      8 * 27 * 256 * 1152,  // V
      27 * 1 * 1152,        // query
      9 * 1152 * 512,       // Wq
      9 * 512,              // bq
      9 * 1152 * 512,       // Wk
      9 * 512,              // bk
      9 * 1152 * 512,       // Wv
      9 * 512,              // bv
      9 * 512 * 2048,       // Wo
      9 * 2048              // bo
    };
    for (int i = 0; i < 11; i++) ok = ok && (in_sizes[i] == expect[i]);
  }
  // ws layout (bytes):
  //   Qp     @ 0          :    55,296
  //   Qk     @ 55,296     :   995,328   [l][d][h]
  //   scores @ 1,050,624  : 1,769,472   [bl][t][h]
  //   attn   @ 2,820,096  : 1,769,472   [bl][t][h]
  //   VA     @ 4,589,568  : 7,962,624   [bl][h][d]
  //   psum   @ 12,552,192 : 1,769,472   [dz][bl][f]
  //   NEED = 14,321,664
  const size_t NEED = 14321664;
  ok = ok && (ws_size >= NEED);

  if (!ok) {
    zfill<<<dim3((out_size + 255) / 256), dim3(256), 0, stream>>>(out, out_size);
    return;
  }

  const float* Kin   = (const float*)d_in[0];
  const float* Vin   = (const float*)d_in[1];
  const float* query = (const float*)d_in[2];
  const float* Wq    = (const float*)d_in[3];
  const float* bq    = (const float*)d_in[4];
  const float* Wk    = (const float*)d_in[5];
  const float* Wv    = (const float*)d_in[7];
  const float* bvp   = (const float*)d_in[8];
  const float* Wo    = (const float*)d_in[9];
  const float* bo    = (const float*)d_in[10];
  // bk (d_in[6]) unused: constant over t, cancels in softmax exactly.

  char* ws = (char*)d_ws;
  float* Qpw     = (float*)(ws);
  float* Qkw     = (float*)(ws + 55296);
  float* scoresw = (float*)(ws + 1050624);
  float* attnw   = (float*)(ws + 2820096);
  float* VAw     = (float*)(ws + 4589568);
  float* psumw   = (float*)(ws + 12552192);

  qproj    <<<dim3(27, 8),    dim3(256), 0, stream>>>(query, Wq, bq, Qpw);
  qk_mat   <<<dim3(3888),     dim3(256), 0, stream>>>(Qpw, Wk, Qkw);
  score_k  <<<dim3(216, 4),   dim3(256), 0, stream>>>(Kin, Qkw, scoresw);
  softmax_k<<<dim3(216),      dim3(256), 0, stream>>>(scoresw, attnw);
  va_k     <<<dim3(216, 3),   dim3(384), 0, stream>>>(Vin, attnw, VAw);
  pv_mat   <<<dim3(27, 8, 4), dim3(512), 0, stream>>>(VAw, Wv, psumw);
  out_gemm <<<dim3(27, 8),    dim3(256), 0, stream>>>(psumw, bvp, Wo, bo, out);
}

// Round 17
// 272.334 us; speedup vs baseline: 1.3302x; 1.0262x over previous
//
#include <hip/hip_runtime.h>
#include <stdint.h>

// ---- dims ----
// B=8, L=27, T=256, D=1152, GS=3, G=9, DD=512, H=8, HD=64, NQ=1, OD=2048
// Output dtype: FLOAT32 (verified round 4).
//
// Round 17: same-mechanism fix in both streamers (conflict-free LDS operand
// supply, no SMEM in hot loops):
//   score_k v4: K staged TRANSPOSED Kt[d][t] stride 65 (bank=(d+lane)%32,
//     conflict-free reads); Qk chunk via wave-uniform LDS broadcast (wave =
//     d-slice); chunk 96 -> LDS 28KB -> 5 blocks/CU (was 2).
//   va_k v2: attn staged to LDS once; inner loop = broadcast b128 reads
//     (in-order DS, pipelinable) instead of out-of-order s_load_dwordx8.
// Algebra (verified r9-r16): scores = K·Qk (bk cancels in softmax);
// pooled = (attn·V)·Wv + bv. All f32.

// ---------------------------------------------------------------------------
// K1: Qp[l,f] = (query[l,:] @ Wq[g] + bq[g]) * 0.125
// grid (27,8), block 256.
// ---------------------------------------------------------------------------
__global__ __launch_bounds__(256) void qproj(
    const float* __restrict__ query, const float* __restrict__ Wq,
    const float* __restrict__ bq, float* __restrict__ Qp)
{
  const int l = blockIdx.x, g = l / 3;
  const int fb = blockIdx.y * 64;
  __shared__ float q[1152];
  __shared__ float part[4][64];
  for (int i = threadIdx.x; i < 1152; i += 256) q[i] = query[(size_t)l * 1152 + i];
  __syncthreads();
  const int fi = threadIdx.x & 63;
  const int kq = threadIdx.x >> 6;            // 0..3, 288 d's each
  const float* W = Wq + (size_t)g * 1152 * 512 + fb + fi;
  float a0 = 0.f, a1 = 0.f;
  const int d0 = kq * 288;
#pragma unroll 4
  for (int d = d0; d < d0 + 288; d += 2) {
    a0 += q[d]     * W[(size_t)d * 512];
    a1 += q[d + 1] * W[(size_t)(d + 1) * 512];
  }
  part[kq][fi] = a0 + a1;
  __syncthreads();
  if (threadIdx.x < 64) {
    const int f = fb + threadIdx.x;
    float r = part[0][threadIdx.x] + part[1][threadIdx.x]
            + part[2][threadIdx.x] + part[3][threadIdx.x];
    Qp[l * 512 + f] = (r + bq[g * 512 + f]) * 0.125f;
  }
}

// ---------------------------------------------------------------------------
// K2: Qk[l,d,h] = sum_e Qp[l,h*64+e] * Wk[g,d,h*64+e]    (layout [l][d][h])
// grid 3888, block 256: 4 threads per (l,h,d), 2-level shuffle reduce.
// ---------------------------------------------------------------------------
__global__ __launch_bounds__(256) void qk_mat(
    const float* __restrict__ Qp, const float* __restrict__ Wk,
    float* __restrict__ Qk)
{
  const int gidx = blockIdx.x * 256 + threadIdx.x;  // 0..995327
  const int eg   = gidx & 3;
  const int item = gidx >> 2;         // 0..248831 = (l,h,d)
  const int l    = item / 9216;
  const int rem  = item % 9216;
  const int h    = rem / 1152;
  const int d    = rem % 1152;
  const int g    = l / 3;
  const float4* q4 = (const float4*)(Qp + l * 512 + h * 64 + eg * 16);
  const float4* w4 = (const float4*)(Wk + (size_t)g * 1152 * 512 + (size_t)d * 512 + h * 64 + eg * 16);
  float acc = 0.f;
#pragma unroll
  for (int e = 0; e < 4; e++) {
    const float4 a = q4[e], b = w4[e];
    acc += a.x * b.x + a.y * b.y + a.z * b.z + a.w * b.w;
  }
  acc += __shfl_xor(acc, 1, 64);
  acc += __shfl_xor(acc, 2, 64);
  if (eg == 0) Qk[((size_t)l * 1152 + d) * 8 + h] = acc;
}

// ---------------------------------------------------------------------------
// K3a: scores[bl][t][h] = sum_d K[bl,t,d] * Qk[l,d,h]   (transposed-LDS)
// grid (216,4 token-tiles), block 256 (4 waves). lane = token, wave = d-slice.
// 12 chunks of 96 d: stage K -> Kt[d][t] stride 65 (conflict-free reads),
// Qk chunk -> Qs (wave-uniform broadcast reads). No SMEM in hot loop.
// LDS 28KB -> 5 blocks/CU.
// ---------------------------------------------------------------------------
__global__ __launch_bounds__(256) void score_k(
    const float* __restrict__ K, const float* __restrict__ Qk,
    float* __restrict__ scores)
{
  const int bl = blockIdx.x;          // 0..215
  const int tq = blockIdx.y;          // 0..3 (64-token tile)
  const int l = bl % 27;
  const int tid = threadIdx.x;
  const int lane = tid & 63;          // token within tile
  const int wid = tid >> 6;           // wave = d-slice (24 d of each 96)

  __shared__ __align__(16) float Kt[96 * 65];   // 24,960 B (d-major); reused for reduce
  __shared__ __align__(16) float Qs[96 * 8];    // 3,072 B

  const float* Kbase = K + ((size_t)bl * 256 + tq * 64) * 1152;
  const float* Qbase = Qk + (size_t)l * 1152 * 8;

  float sc[8] = {0.f, 0.f, 0.f, 0.f, 0.f, 0.f, 0.f, 0.f};

  for (int dc = 0; dc < 12; dc++) {
    __syncthreads();                  // protect LDS from previous reads
    // stage K chunk: 64 tokens x 96 d = 1536 float4; 6 per thread; write
    // transposed (scalar): Kt[d*65 + t]
#pragma unroll
    for (int it = 0; it < 6; it++) {
      const int flat = it * 256 + tid;       // float4 slot
      const int row = flat / 24;             // token
      const int col = flat % 24;             // d4-slot
      const float4 v = *(const float4*)(Kbase + (size_t)row * 1152 + dc * 96 + col * 4);
      Kt[(col * 4 + 0) * 65 + row] = v.x;
      Kt[(col * 4 + 1) * 65 + row] = v.y;
      Kt[(col * 4 + 2) * 65 + row] = v.z;
      Kt[(col * 4 + 3) * 65 + row] = v.w;
    }
    // stage Qk chunk: 96 d x 8 h = 768 floats = 192 float4
    if (tid < 192)
      ((float4*)Qs)[tid] = ((const float4*)(Qbase + (size_t)dc * 96 * 8))[tid];
    __syncthreads();

    // compute: wave wid handles d in [wid*24, wid*24+24)
#pragma unroll 4
    for (int j = 0; j < 24; j++) {
      const int d = wid * 24 + j;
      const float kv = Kt[d * 65 + lane];            // bank=(d+lane)%32: free
      const float4 qa = *(const float4*)&Qs[d * 8];  // wave-uniform broadcast
      const float4 qb = *(const float4*)&Qs[d * 8 + 4];
      sc[0] = fmaf(kv, qa.x, sc[0]); sc[1] = fmaf(kv, qa.y, sc[1]);
      sc[2] = fmaf(kv, qa.z, sc[2]); sc[3] = fmaf(kv, qa.w, sc[3]);
      sc[4] = fmaf(kv, qb.x, sc[4]); sc[5] = fmaf(kv, qb.y, sc[5]);
      sc[6] = fmaf(kv, qb.z, sc[6]); sc[7] = fmaf(kv, qb.w, sc[7]);
    }
  }

  // reduce 4 wave-partials per (t,h) via Kt overlay
  __syncthreads();
  *(float4*)&Kt[(wid * 64 + lane) * 8    ] = make_float4(sc[0], sc[1], sc[2], sc[3]);
  *(float4*)&Kt[(wid * 64 + lane) * 8 + 4] = make_float4(sc[4], sc[5], sc[6], sc[7]);
  __syncthreads();
  for (int out = tid; out < 512; out += 256) {
    const int t = out >> 3, h = out & 7;
    const float s = (Kt[(0 * 64 + t) * 8 + h] + Kt[(1 * 64 + t) * 8 + h])
                  + (Kt[(2 * 64 + t) * 8 + h] + Kt[(3 * 64 + t) * 8 + h]);
    scores[((size_t)bl * 256 + tq * 64 + t) * 8 + h] = s;
  }
}

// ---------------------------------------------------------------------------
// K3b: softmax over 256 tokens per (bl,h). grid 216, block 256 (thread = t).
// attn[bl][t][h].
// ---------------------------------------------------------------------------
__global__ __launch_bounds__(256) void softmax_k(
    const float* __restrict__ scores, float* __restrict__ attn)
{
  const int bl = blockIdx.x;
  const int t = threadIdx.x;
  const int wid = t >> 6, lane = t & 63;
  __shared__ float red[4][8], red2[4][8];

  float sc[8];
  const float* src = scores + ((size_t)bl * 256 + t) * 8;
#pragma unroll
  for (int h = 0; h < 8; h++) sc[h] = src[h];
#pragma unroll
  for (int h = 0; h < 8; h++) {
    float m = sc[h];
#pragma unroll
    for (int o = 1; o < 64; o <<= 1) m = fmaxf(m, __shfl_xor(m, o, 64));
    if (lane == 0) red[wid][h] = m;
  }
  __syncthreads();
  float p[8];
#pragma unroll
  for (int h = 0; h < 8; h++) {
    const float M = fmaxf(fmaxf(red[0][h], red[1][h]), fmaxf(red[2][h], red[3][h]));
    p[h] = __expf(sc[h] - M);
    float s = p[h];
#pragma unroll
    for (int o = 1; o < 64; o <<= 1) s += __shfl_xor(s, o, 64);
    if (lane == 0) red2[wid][h] = s;
  }
  __syncthreads();
  float* dst = attn + ((size_t)bl * 256 + t) * 8;
#pragma unroll
  for (int h = 0; h < 8; h++) {
    const float S = red2[0][h] + red2[1][h] + red2[2][h] + red2[3][h];
    dst[h] = p[h] * (1.0f / S);
  }
}

// ---------------------------------------------------------------------------
// K3c: VA[bl][h][d] = sum_t attn[bl][t][h] * V[bl,t,d]
// grid (216, 3), block 384 (thread = d-element within third).
// attn staged to LDS once (8KB); inner loop = 2 broadcast b128 LDS reads
// per token (in-order DS, pipelinable) + coalesced V load.
// ---------------------------------------------------------------------------
__global__ __launch_bounds__(384) void va_k(
    const float* __restrict__ V, const float* __restrict__ attn,
    float* __restrict__ VA)
{
  const int bl = blockIdx.x;          // 0..215
  const int dt = blockIdx.y;          // 0..2 (d-third of 384)
  const int d  = dt * 384 + threadIdx.x;

  __shared__ __align__(16) float at[2048];   // attn[t][h], 8KB
  for (int i = threadIdx.x; i < 2048; i += 384)
    at[i] = attn[(size_t)bl * 2048 + i];
  __syncthreads();

  const float* Vbase = V + (size_t)bl * 256 * 1152 + d;

  float acc[8] = {0.f, 0.f, 0.f, 0.f, 0.f, 0.f, 0.f, 0.f};
#pragma unroll 4
  for (int t = 0; t < 256; t++) {
    const float v = Vbase[(size_t)t * 1152];
    const float4 a0 = *(const float4*)&at[t * 8];      // broadcast
    const float4 a1 = *(const float4*)&at[t * 8 + 4];  // broadcast
    acc[0] = fmaf(a0.x, v, acc[0]); acc[1] = fmaf(a0.y, v, acc[1]);
    acc[2] = fmaf(a0.z, v, acc[2]); acc[3] = fmaf(a0.w, v, acc[3]);
    acc[4] = fmaf(a1.x, v, acc[4]); acc[5] = fmaf(a1.y, v, acc[5]);
    acc[6] = fmaf(a1.z, v, acc[6]); acc[7] = fmaf(a1.w, v, acc[7]);
  }
  float* dst = VA + (size_t)bl * 8 * 1152 + d;
#pragma unroll
  for (int h = 0; h < 8; h++) dst[(size_t)h * 1152] = acc[h];
}

// ---------------------------------------------------------------------------
// K4: psum[dz][bl][e*8+h] = sum_{d in quarter dz} VA[bl,h,d]*Wv[g,d,h*64+e]
// grid (27,8,4) = (l,h,dz); block 512 = 8 waves (wave = b), lane = e.
// ---------------------------------------------------------------------------
__global__ __launch_bounds__(512) void pv_mat(
    const float* __restrict__ VA, const float* __restrict__ Wv,
    float* __restrict__ psum)
{
  const int l = blockIdx.x, g = l / 3, h = blockIdx.y, dz = blockIdx.z;
  const int b = threadIdx.x >> 6, lane = threadIdx.x & 63;
  const int bl = b * 27 + l;
  const float* W = Wv + (size_t)g * 1152 * 512 + h * 64 + lane;
  const float* va = VA + ((size_t)bl * 8 + h) * 1152;   // wave-uniform
  const int d0 = dz * 288;
  float a0 = 0.f, a1 = 0.f, a2 = 0.f, a3 = 0.f;
#pragma unroll 2
  for (int d = d0; d < d0 + 288; d += 4) {
    a0 = fmaf(va[d],     W[(size_t)(d)     * 512], a0);
    a1 = fmaf(va[d + 1], W[(size_t)(d + 1) * 512], a1);
    a2 = fmaf(va[d + 2], W[(size_t)(d + 2) * 512], a2);
    a3 = fmaf(va[d + 3], W[(size_t)(d + 3) * 512], a3);
  }
  psum[((size_t)dz * 216 + bl) * 512 + lane * 8 + h] = (a0 + a1) + (a2 + a3);
}

// ---------------------------------------------------------------------------
// K5: out[bl,n] = pooled[bl,:]@Wo[g] + bo[g];  pooled = sum_dz psum + bv_perm
// grid (27,8), block 256.
// ---------------------------------------------------------------------------
__global__ __launch_bounds__(256) void out_gemm(
    const float* __restrict__ psum, const float* __restrict__ bv,
    const float* __restrict__ Wo, const float* __restrict__ bo,
    float* __restrict__ out)
{
  const int l = blockIdx.x, g = l / 3;
  const int n = blockIdx.y * 256 + threadIdx.x;
  __shared__ float pl[8][512];
  for (int i = threadIdx.x; i < 4096; i += 256) {
    const int b = i >> 9, f = i & 511;
    const int bl = b * 27 + l;
    const int e = f >> 3, h = f & 7;           // f = e*8 + h
    float v = bv[g * 512 + h * 64 + e];
#pragma unroll
    for (int dz = 0; dz < 4; dz++)
      v += psum[((size_t)dz * 216 + bl) * 512 + f];
    pl[b][f] = v;
  }
  __syncthreads();
  const float* W = Wo + (size_t)g * 512 * 2048 + n;
  float acc[8] = {0.f, 0.f, 0.f, 0.f, 0.f, 0.f, 0.f, 0.f};
#pragma unroll 4
  for (int f = 0; f < 512; f++) {
    const float w = W[(size_t)f * 2048];
#pragma unroll
    for (int b = 0; b < 8; b++) acc[b] += pl[b][f] * w;
  }
  const float bb = bo[g * 2048 + n];
#pragma unroll
  for (int b = 0; b < 8; b++)
    out[(size_t)(b * 27 + l) * 2048 + n] = acc[b] + bb;
}

// ---------------------------------------------------------------------------
// sentinel: zero-fill f32 output (absmax would read ~1.06e-1 = max|ref|)
// ---------------------------------------------------------------------------
__global__ __launch_bounds__(256) void zfill(float* __restrict__ out, int n) {
  const int i = blockIdx.x * 256 + threadIdx.x;
  if (i < n) out[i] = 0.f;
}

// ---------------------------------------------------------------------------
extern "C" void kernel_launch(void* const* d_in, const int* in_sizes, int n_in,
                              void* d_out, int out_size, void* d_ws, size_t ws_size,
                              hipStream_t stream)
{
  float* out = (float*)d_out;   // f32 output (verified round 4)

  // ---- config guards ----
  bool ok = (n_in == 11) && (out_size == 8 * 27 * 2048);
  if (ok) {
    const int expect[11] = {
      8 * 27 * 256 * 1152,  // K
      8 * 27 * 256 * 1152,  // V
      27 * 1 * 1152,        // query
      9 * 1152 * 512,       // Wq
      9 * 512,              // bq
      9 * 1152 * 512,       // Wk
      9 * 512,              // bk
      9 * 1152 * 512,       // Wv
      9 * 512,              // bv
      9 * 512 * 2048,       // Wo
      9 * 2048              // bo
    };
    for (int i = 0; i < 11; i++) ok = ok && (in_sizes[i] == expect[i]);
  }
  // ws layout (bytes):
  //   Qp     @ 0          :    55,296
  //   Qk     @ 55,296     :   995,328   [l][d][h]
  //   scores @ 1,050,624  : 1,769,472   [bl][t][h]
  //   attn   @ 2,820,096  : 1,769,472   [bl][t][h]
  //   VA     @ 4,589,568  : 7,962,624   [bl][h][d]
  //   psum   @ 12,552,192 : 1,769,472   [dz][bl][f]
  //   NEED = 14,321,664
  const size_t NEED = 14321664;
  ok = ok && (ws_size >= NEED);

  if (!ok) {
    zfill<<<dim3((out_size + 255) / 256), dim3(256), 0, stream>>>(out, out_size);
    return;
  }

  const float* Kin   = (const float*)d_in[0];
  const float* Vin   = (const float*)d_in[1];
  const float* query = (const float*)d_in[2];
  const float* Wq    = (const float*)d_in[3];
  const float* bq    = (const float*)d_in[4];
  const float* Wk    = (const float*)d_in[5];
  const float* Wv    = (const float*)d_in[7];
  const float* bvp   = (const float*)d_in[8];
  const float* Wo    = (const float*)d_in[9];
  const float* bo    = (const float*)d_in[10];
  // bk (d_in[6]) unused: constant over t, cancels in softmax exactly.

  char* ws = (char*)d_ws;
  float* Qpw     = (float*)(ws);
  float* Qkw     = (float*)(ws + 55296);
  float* scoresw = (float*)(ws + 1050624);
  float* attnw   = (float*)(ws + 2820096);
  float* VAw     = (float*)(ws + 4589568);
  float* psumw   = (float*)(ws + 12552192);

  qproj    <<<dim3(27, 8),    dim3(256), 0, stream>>>(query, Wq, bq, Qpw);
  qk_mat   <<<dim3(3888),     dim3(256), 0, stream>>>(Qpw, Wk, Qkw);
  score_k  <<<dim3(216, 4),   dim3(256), 0, stream>>>(Kin, Qkw, scoresw);
  softmax_k<<<dim3(216),      dim3(256), 0, stream>>>(scoresw, attnw);
  va_k     <<<dim3(216, 3),   dim3(384), 0, stream>>>(Vin, attnw, VAw);
  pv_mat   <<<dim3(27, 8, 4), dim3(512), 0, stream>>>(VAw, Wv, psumw);
  out_gemm <<<dim3(27, 8),    dim3(256), 0, stream>>>(psumw, bvp, Wo, bo, out);
}

// Round 18
// 268.585 us; speedup vs baseline: 1.3487x; 1.0140x over previous
//
#include <hip/hip_runtime.h>
#include <stdint.h>

// ---- dims ----
// B=8, L=27, T=256, D=1152, GS=3, G=9, DD=512, H=8, HD=64, NQ=1, OD=2048
// Output dtype: FLOAT32 (verified round 4).
//
// Round 18: launch-structure consolidation (tail ~100us of 272 is 5 small
// kernels + 6 serial gaps):
//   qk_fused = qproj + qk_mat   (grid (27,8,3); Qp h-slice recomputed
//              in-block from query·Wq, then r16 qk_mat pattern from LDS)
//   va_sm_k  = softmax_k + va_k (softmax computed in-block from scores,
//              then verbatim r17 va body)
// score_k / pv_mat / out_gemm byte-identical to r17. 7 -> 5 launches.
// Algebra (verified r9-r17): scores = K·Qk (bk cancels in softmax);
// pooled = (attn·V)·Wv + bv. All f32.

// ---------------------------------------------------------------------------
// K1: qk_fused. grid (27,8,3) = (l,h,dc), block 256.
//   phase A: Qps[e] = (query[l,:]·Wq[g,:,h*64+e] + bq[g,h*64+e])*0.125
//   phase B: Qk[l,d,h] = sum_e Qps[e]*Wk[g,d,h*64+e], d in dc*384..+384
//            (r16 qk_mat pattern: 4 threads/output, 2-level shuffle)
// ---------------------------------------------------------------------------
__global__ __launch_bounds__(256) void qk_fused(
    const float* __restrict__ query, const float* __restrict__ Wq,
    const float* __restrict__ bq, const float* __restrict__ Wk,
    float* __restrict__ Qk)
{
  const int l = blockIdx.x, g = l / 3;
  const int h = blockIdx.y;
  const int dc = blockIdx.z;          // 0..2 (384 d each)
  const int tid = threadIdx.x;

  __shared__ float qv[1152];
  __shared__ float part[4][64];
  __shared__ float Qps[64];

  for (int i = tid; i < 1152; i += 256) qv[i] = query[(size_t)l * 1152 + i];
  __syncthreads();

  // phase A: 4-way k-split dot per e  (qproj arithmetic, h-slice only)
  {
    const int e = tid & 63;
    const int kq = tid >> 6;          // 0..3, 288 d' each
    const float* W = Wq + (size_t)g * 1152 * 512 + h * 64 + e;
    float a0 = 0.f, a1 = 0.f;
    const int d0 = kq * 288;
#pragma unroll 4
    for (int d = d0; d < d0 + 288; d += 2) {
      a0 += qv[d]     * W[(size_t)d * 512];
      a1 += qv[d + 1] * W[(size_t)(d + 1) * 512];
    }
    part[kq][e] = a0 + a1;
  }
  __syncthreads();
  if (tid < 64) {
    const float r = part[0][tid] + part[1][tid] + part[2][tid] + part[3][tid];
    Qps[tid] = (r + bq[g * 512 + h * 64 + tid]) * 0.125f;
  }
  __syncthreads();

  // phase B: r16 qk_mat pattern, Qps from LDS
  const float4* q4base = (const float4*)Qps;
#pragma unroll
  for (int it = 0; it < 6; it++) {
    const int slot = it * 256 + tid;  // 0..1535
    const int eg = slot & 3;
    const int d  = dc * 384 + (slot >> 2);
    const float4* q4 = q4base + eg * 4;
    const float4* w4 = (const float4*)(Wk + (size_t)g * 1152 * 512 + (size_t)d * 512 + h * 64 + eg * 16);
    float acc = 0.f;
#pragma unroll
    for (int e = 0; e < 4; e++) {
      const float4 a = q4[e], b = w4[e];
      acc += a.x * b.x + a.y * b.y + a.z * b.z + a.w * b.w;
    }
    acc += __shfl_xor(acc, 1, 64);
    acc += __shfl_xor(acc, 2, 64);
    if (eg == 0) Qk[((size_t)l * 1152 + d) * 8 + h] = acc;
  }
}

// ---------------------------------------------------------------------------
// K2: scores[bl][t][h] = sum_d K[bl,t,d] * Qk[l,d,h]   [verbatim r17]
// grid (216,4 token-tiles), block 256 (4 waves). lane = token, wave = d-slice.
// ---------------------------------------------------------------------------
__global__ __launch_bounds__(256) void score_k(
    const float* __restrict__ K, const float* __restrict__ Qk,
    float* __restrict__ scores)
{
  const int bl = blockIdx.x;          // 0..215
  const int tq = blockIdx.y;          // 0..3 (64-token tile)
  const int l = bl % 27;
  const int tid = threadIdx.x;
  const int lane = tid & 63;          // token within tile
  const int wid = tid >> 6;           // wave = d-slice (24 d of each 96)

  __shared__ __align__(16) float Kt[96 * 65];   // 24,960 B; reused for reduce
  __shared__ __align__(16) float Qs[96 * 8];    // 3,072 B

  const float* Kbase = K + ((size_t)bl * 256 + tq * 64) * 1152;
  const float* Qbase = Qk + (size_t)l * 1152 * 8;

  float sc[8] = {0.f, 0.f, 0.f, 0.f, 0.f, 0.f, 0.f, 0.f};

  for (int dc = 0; dc < 12; dc++) {
    __syncthreads();
#pragma unroll
    for (int it = 0; it < 6; it++) {
      const int flat = it * 256 + tid;       // float4 slot
      const int row = flat / 24;             // token
      const int col = flat % 24;             // d4-slot
      const float4 v = *(const float4*)(Kbase + (size_t)row * 1152 + dc * 96 + col * 4);
      Kt[(col * 4 + 0) * 65 + row] = v.x;
      Kt[(col * 4 + 1) * 65 + row] = v.y;
      Kt[(col * 4 + 2) * 65 + row] = v.z;
      Kt[(col * 4 + 3) * 65 + row] = v.w;
    }
    if (tid < 192)
      ((float4*)Qs)[tid] = ((const float4*)(Qbase + (size_t)dc * 96 * 8))[tid];
    __syncthreads();

#pragma unroll 4
    for (int j = 0; j < 24; j++) {
      const int d = wid * 24 + j;
      const float kv = Kt[d * 65 + lane];            // bank=(d+lane)%32: free
      const float4 qa = *(const float4*)&Qs[d * 8];  // wave-uniform broadcast
      const float4 qb = *(const float4*)&Qs[d * 8 + 4];
      sc[0] = fmaf(kv, qa.x, sc[0]); sc[1] = fmaf(kv, qa.y, sc[1]);
      sc[2] = fmaf(kv, qa.z, sc[2]); sc[3] = fmaf(kv, qa.w, sc[3]);
      sc[4] = fmaf(kv, qb.x, sc[4]); sc[5] = fmaf(kv, qb.y, sc[5]);
      sc[6] = fmaf(kv, qb.z, sc[6]); sc[7] = fmaf(kv, qb.w, sc[7]);
    }
  }

  __syncthreads();
  *(float4*)&Kt[(wid * 64 + lane) * 8    ] = make_float4(sc[0], sc[1], sc[2], sc[3]);
  *(float4*)&Kt[(wid * 64 + lane) * 8 + 4] = make_float4(sc[4], sc[5], sc[6], sc[7]);
  __syncthreads();
  for (int out = tid; out < 512; out += 256) {
    const int t = out >> 3, h = out & 7;
    const float s = (Kt[(0 * 64 + t) * 8 + h] + Kt[(1 * 64 + t) * 8 + h])
                  + (Kt[(2 * 64 + t) * 8 + h] + Kt[(3 * 64 + t) * 8 + h]);
    scores[((size_t)bl * 256 + tq * 64 + t) * 8 + h] = s;
  }
}

// ---------------------------------------------------------------------------
// K3: va_sm_k = softmax (in-block, from scores) + VA.  grid (216,3), blk 384.
//   threads<256: verbatim softmax_k butterfly -> at[] LDS (3x redundant)
//   then verbatim r17 va body (coalesced V, broadcast b128 attn reads).
// ---------------------------------------------------------------------------
__global__ __launch_bounds__(384) void va_sm_k(
    const float* __restrict__ V, const float* __restrict__ scores,
    float* __restrict__ VA)
{
  const int bl = blockIdx.x;          // 0..215
  const int dt = blockIdx.y;          // 0..2 (d-third of 384)
  const int tid = threadIdx.x;
  const int d  = dt * 384 + tid;

  __shared__ __align__(16) float at[2048];   // attn[t][h], 8KB
  __shared__ float red[4][8], red2[4][8];

  const int wid = tid >> 6, lane = tid & 63;
  float sc[8], p[8];
  if (tid < 256) {
    const float* src = scores + ((size_t)bl * 256 + tid) * 8;
#pragma unroll
    for (int h = 0; h < 8; h++) sc[h] = src[h];
#pragma unroll
    for (int h = 0; h < 8; h++) {
      float m = sc[h];
#pragma unroll
      for (int o = 1; o < 64; o <<= 1) m = fmaxf(m, __shfl_xor(m, o, 64));
      if (lane == 0) red[wid][h] = m;
    }
  }
  __syncthreads();
  if (tid < 256) {
#pragma unroll
    for (int h = 0; h < 8; h++) {
      const float M = fmaxf(fmaxf(red[0][h], red[1][h]), fmaxf(red[2][h], red[3][h]));
      p[h] = __expf(sc[h] - M);
      float s = p[h];
#pragma unroll
      for (int o = 1; o < 64; o <<= 1) s += __shfl_xor(s, o, 64);
      if (lane == 0) red2[wid][h] = s;
    }
  }
  __syncthreads();
  if (tid < 256) {
#pragma unroll
    for (int h = 0; h < 8; h++) {
      const float S = red2[0][h] + red2[1][h] + red2[2][h] + red2[3][h];
      at[tid * 8 + h] = p[h] * (1.0f / S);
    }
  }
  __syncthreads();

  // VA body [verbatim r17]
  const float* Vbase = V + (size_t)bl * 256 * 1152 + d;
  float acc[8] = {0.f, 0.f, 0.f, 0.f, 0.f, 0.f, 0.f, 0.f};
#pragma unroll 4
  for (int t = 0; t < 256; t++) {
    const float v = Vbase[(size_t)t * 1152];
    const float4 a0 = *(const float4*)&at[t * 8];      // broadcast
    const float4 a1 = *(const float4*)&at[t * 8 + 4];  // broadcast
    acc[0] = fmaf(a0.x, v, acc[0]); acc[1] = fmaf(a0.y, v, acc[1]);
    acc[2] = fmaf(a0.z, v, acc[2]); acc[3] = fmaf(a0.w, v, acc[3]);
    acc[4] = fmaf(a1.x, v, acc[4]); acc[5] = fmaf(a1.y, v, acc[5]);
    acc[6] = fmaf(a1.z, v, acc[6]); acc[7] = fmaf(a1.w, v, acc[7]);
  }
  float* dst = VA + (size_t)bl * 8 * 1152 + d;
#pragma unroll
  for (int h = 0; h < 8; h++) dst[(size_t)h * 1152] = acc[h];
}

// ---------------------------------------------------------------------------
// K4: psum[dz][bl][e*8+h] = sum_{d in quarter dz} VA[bl,h,d]*Wv[g,d,h*64+e]
// grid (27,8,4) = (l,h,dz); block 512 = 8 waves (wave = b), lane = e.
// [verbatim r17]
// ---------------------------------------------------------------------------
__global__ __launch_bounds__(512) void pv_mat(
    const float* __restrict__ VA, const float* __restrict__ Wv,
    float* __restrict__ psum)
{
  const int l = blockIdx.x, g = l / 3, h = blockIdx.y, dz = blockIdx.z;
  const int b = threadIdx.x >> 6, lane = threadIdx.x & 63;
  const int bl = b * 27 + l;
  const float* W = Wv + (size_t)g * 1152 * 512 + h * 64 + lane;
  const float* va = VA + ((size_t)bl * 8 + h) * 1152;   // wave-uniform
  const int d0 = dz * 288;
  float a0 = 0.f, a1 = 0.f, a2 = 0.f, a3 = 0.f;
#pragma unroll 2
  for (int d = d0; d < d0 + 288; d += 4) {
    a0 = fmaf(va[d],     W[(size_t)(d)     * 512], a0);
    a1 = fmaf(va[d + 1], W[(size_t)(d + 1) * 512], a1);
    a2 = fmaf(va[d + 2], W[(size_t)(d + 2) * 512], a2);
    a3 = fmaf(va[d + 3], W[(size_t)(d + 3) * 512], a3);
  }
  psum[((size_t)dz * 216 + bl) * 512 + lane * 8 + h] = (a0 + a1) + (a2 + a3);
}

// ---------------------------------------------------------------------------
// K5: out[bl,n] = pooled[bl,:]@Wo[g] + bo[g];  pooled = sum_dz psum + bv_perm
// grid (27,8), block 256.  [verbatim r17]
// ---------------------------------------------------------------------------
__global__ __launch_bounds__(256) void out_gemm(
    const float* __restrict__ psum, const float* __restrict__ bv,
    const float* __restrict__ Wo, const float* __restrict__ bo,
    float* __restrict__ out)
{
  const int l = blockIdx.x, g = l / 3;
  const int n = blockIdx.y * 256 + threadIdx.x;
  __shared__ float pl[8][512];
  for (int i = threadIdx.x; i < 4096; i += 256) {
    const int b = i >> 9, f = i & 511;
    const int bl = b * 27 + l;
    const int e = f >> 3, h = f & 7;           // f = e*8 + h
    float v = bv[g * 512 + h * 64 + e];
#pragma unroll
    for (int dz = 0; dz < 4; dz++)
      v += psum[((size_t)dz * 216 + bl) * 512 + f];
    pl[b][f] = v;
  }
  __syncthreads();
  const float* W = Wo + (size_t)g * 512 * 2048 + n;
  float acc[8] = {0.f, 0.f, 0.f, 0.f, 0.f, 0.f, 0.f, 0.f};
#pragma unroll 4
  for (int f = 0; f < 512; f++) {
    const float w = W[(size_t)f * 2048];
#pragma unroll
    for (int b = 0; b < 8; b++) acc[b] += pl[b][f] * w;
  }
  const float bb = bo[g * 2048 + n];
#pragma unroll
  for (int b = 0; b < 8; b++)
    out[(size_t)(b * 27 + l) * 2048 + n] = acc[b] + bb;
}

// ---------------------------------------------------------------------------
// sentinel: zero-fill f32 output (absmax would read ~1.06e-1 = max|ref|)
// ---------------------------------------------------------------------------
__global__ __launch_bounds__(256) void zfill(float* __restrict__ out, int n) {
  const int i = blockIdx.x * 256 + threadIdx.x;
  if (i < n) out[i] = 0.f;
}

// ---------------------------------------------------------------------------
extern "C" void kernel_launch(void* const* d_in, const int* in_sizes, int n_in,
                              void* d_out, int out_size, void* d_ws, size_t ws_size,
                              hipStream_t stream)
{
  float* out = (float*)d_out;   // f32 output (verified round 4)

  // ---- config guards ----
  bool ok = (n_in == 11) && (out_size == 8 * 27 * 2048);
  if (ok) {
    const int expect[11] = {
      8 * 27 * 256 * 1152,  // K
      8 * 27 * 256 * 1152,  // V
      27 * 1 * 1152,        // query
      9 * 1152 * 512,       // Wq
      9 * 512,              // bq
      9 * 1152 * 512,       // Wk
      9 * 512,              // bk
      9 * 1152 * 512,       // Wv
      9 * 512,              // bv
      9 * 512 * 2048,       // Wo
      9 * 2048              // bo
    };
    for (int i = 0; i < 11; i++) ok = ok && (in_sizes[i] == expect[i]);
  }
  // ws layout (bytes):
  //   Qk     @ 55,296     :   995,328   [l][d][h]   (Qp slot retired)
  //   scores @ 1,050,624  : 1,769,472   [bl][t][h]
  //   VA     @ 4,589,568  : 7,962,624   [bl][h][d]
  //   psum   @ 12,552,192 : 1,769,472   [dz][bl][f]
  //   NEED = 14,321,664 (layout kept from r17)
  const size_t NEED = 14321664;
  ok = ok && (ws_size >= NEED);

  if (!ok) {
    zfill<<<dim3((out_size + 255) / 256), dim3(256), 0, stream>>>(out, out_size);
    return;
  }

  const float* Kin   = (const float*)d_in[0];
  const float* Vin   = (const float*)d_in[1];
  const float* query = (const float*)d_in[2];
  const float* Wq    = (const float*)d_in[3];
  const float* bq    = (const float*)d_in[4];
  const float* Wk    = (const float*)d_in[5];
  const float* Wv    = (const float*)d_in[7];
  const float* bvp   = (const float*)d_in[8];
  const float* Wo    = (const float*)d_in[9];
  const float* bo    = (const float*)d_in[10];
  // bk (d_in[6]) unused: constant over t, cancels in softmax exactly.

  char* ws = (char*)d_ws;
  float* Qkw     = (float*)(ws + 55296);
  float* scoresw = (float*)(ws + 1050624);
  float* VAw     = (float*)(ws + 4589568);
  float* psumw   = (float*)(ws + 12552192);

  qk_fused<<<dim3(27, 8, 3), dim3(256), 0, stream>>>(query, Wq, bq, Wk, Qkw);
  score_k <<<dim3(216, 4),   dim3(256), 0, stream>>>(Kin, Qkw, scoresw);
  va_sm_k <<<dim3(216, 3),   dim3(384), 0, stream>>>(Vin, scoresw, VAw);
  pv_mat  <<<dim3(27, 8, 4), dim3(512), 0, stream>>>(VAw, Wv, psumw);
  out_gemm<<<dim3(27, 8),    dim3(256), 0, stream>>>(psumw, bvp, Wo, bo, out);
}

// Round 19
// 262.217 us; speedup vs baseline: 1.3815x; 1.0243x over previous
//
#include <hip/hip_runtime.h>
#include <stdint.h>

// ---- dims ----
// B=8, L=27, T=256, D=1152, GS=3, G=9, DD=512, H=8, HD=64, NQ=1, OD=2048
// Output dtype: FLOAT32 (verified round 4).
//
// Round 19: memory-level-parallelism fixes in both streamers (r18 analysis:
// streamers run 2.4-3 TB/s vs fill's 6.9 because loads drain before compute):
//   score_k : async-STAGE split (T14) -- prefetch chunk dc+1 into regs
//             during compute of chunk dc; loads in flight across compute.
//   va_sm_k : t-loop unroll 4 -> 16 (64B outstanding/thread).
// All else verbatim r18. Algebra (verified r9-r18): scores = K·Qk (bk
// cancels in softmax); pooled = (attn·V)·Wv + bv. All f32.

// ---------------------------------------------------------------------------
// K1: qk_fused. grid (27,8,3) = (l,h,dc), block 256.  [verbatim r18]
// ---------------------------------------------------------------------------
__global__ __launch_bounds__(256) void qk_fused(
    const float* __restrict__ query, const float* __restrict__ Wq,
    const float* __restrict__ bq, const float* __restrict__ Wk,
    float* __restrict__ Qk)
{
  const int l = blockIdx.x, g = l / 3;
  const int h = blockIdx.y;
  const int dc = blockIdx.z;          // 0..2 (384 d each)
  const int tid = threadIdx.x;

  __shared__ float qv[1152];
  __shared__ float part[4][64];
  __shared__ float Qps[64];

  for (int i = tid; i < 1152; i += 256) qv[i] = query[(size_t)l * 1152 + i];
  __syncthreads();

  {
    const int e = tid & 63;
    const int kq = tid >> 6;          // 0..3, 288 d' each
    const float* W = Wq + (size_t)g * 1152 * 512 + h * 64 + e;
    float a0 = 0.f, a1 = 0.f;
    const int d0 = kq * 288;
#pragma unroll 4
    for (int d = d0; d < d0 + 288; d += 2) {
      a0 += qv[d]     * W[(size_t)d * 512];
      a1 += qv[d + 1] * W[(size_t)(d + 1) * 512];
    }
    part[kq][e] = a0 + a1;
  }
  __syncthreads();
  if (tid < 64) {
    const float r = part[0][tid] + part[1][tid] + part[2][tid] + part[3][tid];
    Qps[tid] = (r + bq[g * 512 + h * 64 + tid]) * 0.125f;
  }
  __syncthreads();

  const float4* q4base = (const float4*)Qps;
#pragma unroll
  for (int it = 0; it < 6; it++) {
    const int slot = it * 256 + tid;  // 0..1535
    const int eg = slot & 3;
    const int d  = dc * 384 + (slot >> 2);
    const float4* q4 = q4base + eg * 4;
    const float4* w4 = (const float4*)(Wk + (size_t)g * 1152 * 512 + (size_t)d * 512 + h * 64 + eg * 16);
    float acc = 0.f;
#pragma unroll
    for (int e = 0; e < 4; e++) {
      const float4 a = q4[e], b = w4[e];
      acc += a.x * b.x + a.y * b.y + a.z * b.z + a.w * b.w;
    }
    acc += __shfl_xor(acc, 1, 64);
    acc += __shfl_xor(acc, 2, 64);
    if (eg == 0) Qk[((size_t)l * 1152 + d) * 8 + h] = acc;
  }
}

// ---------------------------------------------------------------------------
// K2: scores[bl][t][h] = sum_d K[bl,t,d] * Qk[l,d,h]
// grid (216,4 token-tiles), block 256 (4 waves). lane = token, wave = d-slice.
// r17 transposed-LDS structure + T14 async-STAGE: prefetch chunk dc+1 into
// regs (6x float4 K + 1 float4 Qs) during compute of chunk dc.
// ---------------------------------------------------------------------------
__global__ __launch_bounds__(256) void score_k(
    const float* __restrict__ K, const float* __restrict__ Qk,
    float* __restrict__ scores)
{
  const int bl = blockIdx.x;          // 0..215
  const int tq = blockIdx.y;          // 0..3 (64-token tile)
  const int l = bl % 27;
  const int tid = threadIdx.x;
  const int lane = tid & 63;          // token within tile
  const int wid = tid >> 6;           // wave = d-slice (24 d of each 96)

  __shared__ __align__(16) float Kt[96 * 65];   // 24,960 B; reused for reduce
  __shared__ __align__(16) float Qs[96 * 8];    // 3,072 B

  const float* Kbase = K + ((size_t)bl * 256 + tq * 64) * 1152;
  const float* Qbase = Qk + (size_t)l * 1152 * 8;

  // staging-slot geometry (fixed per thread)
  const int srow = tid / 24 * 0;  // placeholder to keep naming clear below
  float4 kreg[6];
  float4 qreg;

  auto loadChunk = [&](int dc) {
#pragma unroll
    for (int it = 0; it < 6; it++) {
      const int flat = it * 256 + tid;       // float4 slot
      const int row = flat / 24;             // token
      const int col = flat % 24;             // d4-slot
      kreg[it] = *(const float4*)(Kbase + (size_t)row * 1152 + dc * 96 + col * 4);
    }
    if (tid < 192)
      qreg = ((const float4*)(Qbase + (size_t)dc * 96 * 8))[tid];
  };
  auto storeChunk = [&]() {
#pragma unroll
    for (int it = 0; it < 6; it++) {
      const int flat = it * 256 + tid;
      const int row = flat / 24;
      const int col = flat % 24;
      Kt[(col * 4 + 0) * 65 + row] = kreg[it].x;
      Kt[(col * 4 + 1) * 65 + row] = kreg[it].y;
      Kt[(col * 4 + 2) * 65 + row] = kreg[it].z;
      Kt[(col * 4 + 3) * 65 + row] = kreg[it].w;
    }
    if (tid < 192)
      ((float4*)Qs)[tid] = qreg;
  };

  float sc[8] = {0.f, 0.f, 0.f, 0.f, 0.f, 0.f, 0.f, 0.f};

  loadChunk(0);
  for (int dc = 0; dc < 12; dc++) {
    storeChunk();
    __syncthreads();
    if (dc + 1 < 12) loadChunk(dc + 1);   // loads fly over compute
    // compute: wave wid handles d in [wid*24, wid*24+24)
#pragma unroll 4
    for (int j = 0; j < 24; j++) {
      const int d = wid * 24 + j;
      const float kv = Kt[d * 65 + lane];            // bank=(d+lane)%32: free
      const float4 qa = *(const float4*)&Qs[d * 8];  // wave-uniform broadcast
      const float4 qb = *(const float4*)&Qs[d * 8 + 4];
      sc[0] = fmaf(kv, qa.x, sc[0]); sc[1] = fmaf(kv, qa.y, sc[1]);
      sc[2] = fmaf(kv, qa.z, sc[2]); sc[3] = fmaf(kv, qa.w, sc[3]);
      sc[4] = fmaf(kv, qb.x, sc[4]); sc[5] = fmaf(kv, qb.y, sc[5]);
      sc[6] = fmaf(kv, qb.z, sc[6]); sc[7] = fmaf(kv, qb.w, sc[7]);
    }
    __syncthreads();
  }
  (void)srow;

  // reduce 4 wave-partials per (t,h) via Kt overlay
  *(float4*)&Kt[(wid * 64 + lane) * 8    ] = make_float4(sc[0], sc[1], sc[2], sc[3]);
  *(float4*)&Kt[(wid * 64 + lane) * 8 + 4] = make_float4(sc[4], sc[5], sc[6], sc[7]);
  __syncthreads();
  for (int out = tid; out < 512; out += 256) {
    const int t = out >> 3, h = out & 7;
    const float s = (Kt[(0 * 64 + t) * 8 + h] + Kt[(1 * 64 + t) * 8 + h])
                  + (Kt[(2 * 64 + t) * 8 + h] + Kt[(3 * 64 + t) * 8 + h]);
    scores[((size_t)bl * 256 + tq * 64 + t) * 8 + h] = s;
  }
}

// ---------------------------------------------------------------------------
// K3: va_sm_k = softmax (in-block) + VA.  grid (216,3), blk 384.
// r18 structure; t-loop unroll 16 (64B outstanding per thread).
// ---------------------------------------------------------------------------
__global__ __launch_bounds__(384) void va_sm_k(
    const float* __restrict__ V, const float* __restrict__ scores,
    float* __restrict__ VA)
{
  const int bl = blockIdx.x;          // 0..215
  const int dt = blockIdx.y;          // 0..2 (d-third of 384)
  const int tid = threadIdx.x;
  const int d  = dt * 384 + tid;

  __shared__ __align__(16) float at[2048];   // attn[t][h], 8KB
  __shared__ float red[4][8], red2[4][8];

  const int wid = tid >> 6, lane = tid & 63;
  float sc[8], p[8];
  if (tid < 256) {
    const float* src = scores + ((size_t)bl * 256 + tid) * 8;
#pragma unroll
    for (int h = 0; h < 8; h++) sc[h] = src[h];
#pragma unroll
    for (int h = 0; h < 8; h++) {
      float m = sc[h];
#pragma unroll
      for (int o = 1; o < 64; o <<= 1) m = fmaxf(m, __shfl_xor(m, o, 64));
      if (lane == 0) red[wid][h] = m;
    }
  }
  __syncthreads();
  if (tid < 256) {
#pragma unroll
    for (int h = 0; h < 8; h++) {
      const float M = fmaxf(fmaxf(red[0][h], red[1][h]), fmaxf(red[2][h], red[3][h]));
      p[h] = __expf(sc[h] - M);
      float s = p[h];
#pragma unroll
      for (int o = 1; o < 64; o <<= 1) s += __shfl_xor(s, o, 64);
      if (lane == 0) red2[wid][h] = s;
    }
  }
  __syncthreads();
  if (tid < 256) {
#pragma unroll
    for (int h = 0; h < 8; h++) {
      const float S = red2[0][h] + red2[1][h] + red2[2][h] + red2[3][h];
      at[tid * 8 + h] = p[h] * (1.0f / S);
    }
  }
  __syncthreads();

  // VA body: unroll 16 for memory-level parallelism
  const float* Vbase = V + (size_t)bl * 256 * 1152 + d;
  float acc[8] = {0.f, 0.f, 0.f, 0.f, 0.f, 0.f, 0.f, 0.f};
#pragma unroll 16
  for (int t = 0; t < 256; t++) {
    const float v = Vbase[(size_t)t * 1152];
    const float4 a0 = *(const float4*)&at[t * 8];      // broadcast
    const float4 a1 = *(const float4*)&at[t * 8 + 4];  // broadcast
    acc[0] = fmaf(a0.x, v, acc[0]); acc[1] = fmaf(a0.y, v, acc[1]);
    acc[2] = fmaf(a0.z, v, acc[2]); acc[3] = fmaf(a0.w, v, acc[3]);
    acc[4] = fmaf(a1.x, v, acc[4]); acc[5] = fmaf(a1.y, v, acc[5]);
    acc[6] = fmaf(a1.z, v, acc[6]); acc[7] = fmaf(a1.w, v, acc[7]);
  }
  float* dst = VA + (size_t)bl * 8 * 1152 + d;
#pragma unroll
  for (int h = 0; h < 8; h++) dst[(size_t)h * 1152] = acc[h];
}

// ---------------------------------------------------------------------------
// K4: psum[dz][bl][e*8+h] = sum_{d in quarter dz} VA[bl,h,d]*Wv[g,d,h*64+e]
// grid (27,8,4) = (l,h,dz); block 512.  [verbatim r18]
// ---------------------------------------------------------------------------
__global__ __launch_bounds__(512) void pv_mat(
    const float* __restrict__ VA, const float* __restrict__ Wv,
    float* __restrict__ psum)
{
  const int l = blockIdx.x, g = l / 3, h = blockIdx.y, dz = blockIdx.z;
  const int b = threadIdx.x >> 6, lane = threadIdx.x & 63;
  const int bl = b * 27 + l;
  const float* W = Wv + (size_t)g * 1152 * 512 + h * 64 + lane;
  const float* va = VA + ((size_t)bl * 8 + h) * 1152;   // wave-uniform
  const int d0 = dz * 288;
  float a0 = 0.f, a1 = 0.f, a2 = 0.f, a3 = 0.f;
#pragma unroll 2
  for (int d = d0; d < d0 + 288; d += 4) {
    a0 = fmaf(va[d],     W[(size_t)(d)     * 512], a0);
    a1 = fmaf(va[d + 1], W[(size_t)(d + 1) * 512], a1);
    a2 = fmaf(va[d + 2], W[(size_t)(d + 2) * 512], a2);
    a3 = fmaf(va[d + 3], W[(size_t)(d + 3) * 512], a3);
  }
  psum[((size_t)dz * 216 + bl) * 512 + lane * 8 + h] = (a0 + a1) + (a2 + a3);
}

// ---------------------------------------------------------------------------
// K5: out[bl,n] = pooled[bl,:]@Wo[g] + bo[g];  pooled = sum_dz psum + bv_perm
// grid (27,8), block 256.  [verbatim r18]
// ---------------------------------------------------------------------------
__global__ __launch_bounds__(256) void out_gemm(
    const float* __restrict__ psum, const float* __restrict__ bv,
    const float* __restrict__ Wo, const float* __restrict__ bo,
    float* __restrict__ out)
{
  const int l = blockIdx.x, g = l / 3;
  const int n = blockIdx.y * 256 + threadIdx.x;
  __shared__ float pl[8][512];
  for (int i = threadIdx.x; i < 4096; i += 256) {
    const int b = i >> 9, f = i & 511;
    const int bl = b * 27 + l;
    const int e = f >> 3, h = f & 7;           // f = e*8 + h
    float v = bv[g * 512 + h * 64 + e];
#pragma unroll
    for (int dz = 0; dz < 4; dz++)
      v += psum[((size_t)dz * 216 + bl) * 512 + f];
    pl[b][f] = v;
  }
  __syncthreads();
  const float* W = Wo + (size_t)g * 512 * 2048 + n;
  float acc[8] = {0.f, 0.f, 0.f, 0.f, 0.f, 0.f, 0.f, 0.f};
#pragma unroll 4
  for (int f = 0; f < 512; f++) {
    const float w = W[(size_t)f * 2048];
#pragma unroll
    for (int b = 0; b < 8; b++) acc[b] += pl[b][f] * w;
  }
  const float bb = bo[g * 2048 + n];
#pragma unroll
  for (int b = 0; b < 8; b++)
    out[(size_t)(b * 27 + l) * 2048 + n] = acc[b] + bb;
}

// ---------------------------------------------------------------------------
// sentinel: zero-fill f32 output (absmax would read ~1.06e-1 = max|ref|)
// ---------------------------------------------------------------------------
__global__ __launch_bounds__(256) void zfill(float* __restrict__ out, int n) {
  const int i = blockIdx.x * 256 + threadIdx.x;
  if (i < n) out[i] = 0.f;
}

// ---------------------------------------------------------------------------
extern "C" void kernel_launch(void* const* d_in, const int* in_sizes, int n_in,
                              void* d_out, int out_size, void* d_ws, size_t ws_size,
                              hipStream_t stream)
{
  float* out = (float*)d_out;   // f32 output (verified round 4)

  // ---- config guards ----
  bool ok = (n_in == 11) && (out_size == 8 * 27 * 2048);
  if (ok) {
    const int expect[11] = {
      8 * 27 * 256 * 1152,  // K
      8 * 27 * 256 * 1152,  // V
      27 * 1 * 1152,        // query
      9 * 1152 * 512,       // Wq
      9 * 512,              // bq
      9 * 1152 * 512,       // Wk
      9 * 512,              // bk
      9 * 1152 * 512,       // Wv
      9 * 512,              // bv
      9 * 512 * 2048,       // Wo
      9 * 2048              // bo
    };
    for (int i = 0; i < 11; i++) ok = ok && (in_sizes[i] == expect[i]);
  }
  const size_t NEED = 14321664;
  ok = ok && (ws_size >= NEED);

  if (!ok) {
    zfill<<<dim3((out_size + 255) / 256), dim3(256), 0, stream>>>(out, out_size);
    return;
  }

  const float* Kin   = (const float*)d_in[0];
  const float* Vin   = (const float*)d_in[1];
  const float* query = (const float*)d_in[2];
  const float* Wq    = (const float*)d_in[3];
  const float* bq    = (const float*)d_in[4];
  const float* Wk    = (const float*)d_in[5];
  const float* Wv    = (const float*)d_in[7];
  const float* bvp   = (const float*)d_in[8];
  const float* Wo    = (const float*)d_in[9];
  const float* bo    = (const float*)d_in[10];
  // bk (d_in[6]) unused: constant over t, cancels in softmax exactly.

  char* ws = (char*)d_ws;
  float* Qkw     = (float*)(ws + 55296);
  float* scoresw = (float*)(ws + 1050624);
  float* VAw     = (float*)(ws + 4589568);
  float* psumw   = (float*)(ws + 12552192);

  qk_fused<<<dim3(27, 8, 3), dim3(256), 0, stream>>>(query, Wq, bq, Wk, Qkw);
  score_k <<<dim3(216, 4),   dim3(256), 0, stream>>>(Kin, Qkw, scoresw);
  va_sm_k <<<dim3(216, 3),   dim3(384), 0, stream>>>(Vin, scoresw, VAw);
  pv_mat  <<<dim3(27, 8, 4), dim3(512), 0, stream>>>(VAw, Wv, psumw);
  out_gemm<<<dim3(27, 8),    dim3(256), 0, stream>>>(psumw, bvp, Wo, bo, out);
}